// Round 8
// baseline (187.668 us; speedup 1.0000x reference)
//
#include <hip/hip_runtime.h>
#include <hip/hip_bf16.h>

// Problem constants: B=2, T=4096, E=512, H=8, D=64
#define T_SEQ 4096
#define EMB   512
#define NH    8
#define HD    64
#define BATCH 2
#define M_ROWS (BATCH * T_SEQ)   // 8192
#define NCHUNK 64                // T / CS
#define CS     64                // chunk size
#define BHEADS (BATCH * NH)      // 16

using bf16 = __hip_bfloat16;
typedef __attribute__((ext_vector_type(8))) short short8;   // 8 bf16 = 4 VGPR
typedef __attribute__((ext_vector_type(4))) short short4v;  // 8B LDS store
typedef __attribute__((ext_vector_type(4))) float floatx4;  // MFMA acc

__device__ __forceinline__ float bs2f(short s) {
    return __uint_as_float(((unsigned)(unsigned short)s) << 16);
}
__device__ __forceinline__ short f2bs(float f) {
    bf16 h = __float2bfloat16(f);
    return *reinterpret_cast<short*>(&h);
}
__device__ __forceinline__ float load_elem(const bf16* p, size_t i) {
    return __bfloat162float(p[i]);
}
// convert 8 consecutive elems (any dtype) -> bf16, 16B write
__device__ __forceinline__ void stage8(const bf16* g, short* l) {
    *reinterpret_cast<short8*>(l) = *reinterpret_cast<const short8*>(g);
}
__device__ __forceinline__ void stage8(const float* g, short* l) {
    float4 a = *reinterpret_cast<const float4*>(g);
    float4 b = *reinterpret_cast<const float4*>(g + 4);
    short8 v;
    v[0] = f2bs(a.x); v[1] = f2bs(a.y); v[2] = f2bs(a.z); v[3] = f2bs(a.w);
    v[4] = f2bs(b.x); v[5] = f2bs(b.y); v[6] = f2bs(b.z); v[7] = f2bs(b.w);
    *reinterpret_cast<short8*>(l) = v;
}

#define LDSTR 72   // padded LDS row stride (shorts) for transposed tiles

// ---------------------------------------------------------------------------
// In-block dtype probe (validated round 7).  1 = fp32, 0 = bf16.
// ---------------------------------------------------------------------------
__device__ __forceinline__ int probe_mode(const void* x) {
    const uint4* p = (const uint4*)x;
    const int tid = threadIdx.x;
    bool bad = false;
    #pragma unroll
    for (int i = 0; i < 2; ++i) {
        uint4 u = p[tid + i * 256];
        const unsigned w[4] = {u.x, u.y, u.z, u.w};
        #pragma unroll
        for (int k = 0; k < 4; ++k) {
            const float f = __uint_as_float(w[k] << 16);   // low half
            if (!(fabsf(f) <= 1e9f)) bad = true;
        }
    }
    return __syncthreads_or(bad ? 1 : 0) ? 1 : 0;
}

// ---------------------------------------------------------------------------
// Kernel 1: convert x, Wq/Wk/Wv/Wo, biases -> bf16 ws (validated round 7).
// ---------------------------------------------------------------------------
template <typename T>
__device__ __forceinline__ void convert_body(
    const void* const* in, short* xb, short* Wb, short* bb, int c)
{
    if (c < 524288) {
        stage8((const T*)in[0] + (size_t)c * 8, xb + (size_t)c * 8);
    } else if (c < 655360) {
        const int c2 = c - 524288;
        const int w = c2 >> 15;             // 0..3 : Wq Wk Wv Wo
        const int off = (c2 & 32767) * 8;
        const T* src = (const T*)in[w == 0 ? 1 : (w == 1 ? 3 : (w == 2 ? 5 : 7))];
        stage8(src + off, Wb + w * 262144 + off);
    } else if (c < 655616) {
        const int c3 = c - 655360;          // 0..255
        const int bsel = c3 >> 6;
        const int off = (c3 & 63) * 8;
        const T* src = (const T*)in[bsel == 0 ? 2 : (bsel == 1 ? 4 : (bsel == 2 ? 6 : 8))];
        stage8(src + off, bb + bsel * 512 + off);
    }
}

__global__ __launch_bounds__(256) void convert_all(
    const void* x, const void* Wq, const void* bq,
    const void* Wk, const void* bk, const void* Wv, const void* bv,
    const void* Wo, const void* bo,
    short* __restrict__ xb, short* __restrict__ Wb, short* __restrict__ bb)
{
    const void* in[9] = {x, Wq, bq, Wk, bk, Wv, bv, Wo, bo};
    const int mode = probe_mode(x);
    const int c = blockIdx.x * 256 + threadIdx.x;
    if (mode) convert_body<float>(in, xb, Wb, bb, c);
    else      convert_body<bf16>(in, xb, Wb, bb, c);
}

// ---------------------------------------------------------------------------
// Kernel 2: fused QKV projection — LDS-FREE direct-fragment GEMM.
// Each lane loads its MFMA fragments (16B) straight from global (L2-hot
// x/W); no LDS staging, no barriers -> compiler interleaves buffer_load与MFMA
// with fine-grained vmcnt (the AITER pattern).  Grid (64,12); y>>2 = Q/K/V.
// ---------------------------------------------------------------------------
__global__ __launch_bounds__(256) void qkv_direct(
    const short* __restrict__ xb, const short* __restrict__ Wb,
    const short* __restrict__ bb,
    bf16* __restrict__ Qf, bf16* __restrict__ Kf, bf16* __restrict__ Vf)
{
    const int mtile = blockIdx.x;            // 0..63
    const int ntile = blockIdx.y;            // 0..11
    const int which = ntile >> 2;
    const short* W = Wb + (size_t)which * 262144;
    const bf16* bias = (const bf16*)(bb + which * 512);
    bf16* outp = (which == 0) ? Qf : ((which == 1) ? Kf : Vf);
    const int nbase = (ntile & 3) * 128;
    const int mbase = mtile * 128;

    const int tid  = threadIdx.x;
    const int wave = tid >> 6, lane = tid & 63;
    const int wm = wave >> 1, wn = wave & 1;
    const int lm = lane & 15, quad = lane >> 4;

    // per-lane fragment base offsets (K-major, row stride EMB shorts)
    const size_t abase = (size_t)(mbase + wm * 64 + lm) * EMB + quad * 8;
    const size_t bbase = (size_t)(nbase + wn * 64 + lm) * EMB + quad * 8;

    floatx4 acc[4][4];
    const floatx4 zero = {0.f, 0.f, 0.f, 0.f};
    #pragma unroll
    for (int mt = 0; mt < 4; ++mt)
        #pragma unroll
        for (int nt = 0; nt < 4; ++nt) acc[mt][nt] = zero;

    for (int kt = 0; kt < EMB; kt += 64) {
        short8 af[4][2], bf[4][2];
        #pragma unroll
        for (int mt = 0; mt < 4; ++mt)
            #pragma unroll
            for (int ks = 0; ks < 2; ++ks)
                af[mt][ks] = *reinterpret_cast<const short8*>(
                    xb + abase + (size_t)mt * 16 * EMB + kt + ks * 32);
        #pragma unroll
        for (int nt = 0; nt < 4; ++nt)
            #pragma unroll
            for (int ks = 0; ks < 2; ++ks)
                bf[nt][ks] = *reinterpret_cast<const short8*>(
                    W + bbase + (size_t)nt * 16 * EMB + kt + ks * 32);
        #pragma unroll
        for (int ks = 0; ks < 2; ++ks)
            #pragma unroll
            for (int mt = 0; mt < 4; ++mt)
                #pragma unroll
                for (int nt = 0; nt < 4; ++nt)
                    acc[mt][nt] = __builtin_amdgcn_mfma_f32_16x16x32_bf16(
                        af[mt][ks], bf[nt][ks], acc[mt][nt], 0, 0, 0);
    }

    #pragma unroll
    for (int nt = 0; nt < 4; ++nt) {
        const int col = nbase + wn * 64 + nt * 16 + lm;   // 0..511
        const float bv_ = load_elem(bias, col & 511);
        const int h = col >> 6, d = col & 63;
        #pragma unroll
        for (int mt = 0; mt < 4; ++mt)
            #pragma unroll
            for (int r = 0; r < 4; ++r) {
                const int row = mbase + wm * 64 + mt * 16 + quad * 4 + r;
                const int b = row >> 12, t = row & (T_SEQ - 1);
                float v = acc[mt][nt][r] + bv_;
                if (which != 2) v = (v > 0.f) ? (v + 1.f) : __expf(v);  // elu+1
                outp[(((size_t)(b * NH + h)) * T_SEQ + t) * HD + d] = __float2bfloat16(v);
            }
    }
}

// ---------------------------------------------------------------------------
// Kernel 3: per-chunk (K^T V)^T via MFMA + k column sums (validated r7).
// ---------------------------------------------------------------------------
__global__ __launch_bounds__(256) void chunk_kv(
    const bf16* __restrict__ Kf, const bf16* __restrict__ Vf,
    float* __restrict__ KVt, float* __restrict__ ksum)
{
    const int bh = blockIdx.x >> 6;
    const int c  = blockIdx.x & 63;
    __shared__ short Kt[64 * LDSTR];   // Kt[dk][s]
    __shared__ short Vt[64 * LDSTR];   // Vt[dv][s]
    const int tid = threadIdx.x;
    const bf16* kp = Kf + ((size_t)bh * T_SEQ + c * CS) * HD;
    const bf16* vp = Vf + ((size_t)bh * T_SEQ + c * CS) * HD;

    #pragma unroll
    for (int j = 0; j < 2; ++j) {
        const int u = j * 256 + tid;
        const int e0 = u * 8;
        const int s = e0 >> 6, d0 = e0 & 63;
        short8 ku = *reinterpret_cast<const short8*>(kp + e0);
        short8 vu = *reinterpret_cast<const short8*>(vp + e0);
        #pragma unroll
        for (int i = 0; i < 8; ++i) {
            Kt[(d0 + i) * LDSTR + s] = ku[i];
            Vt[(d0 + i) * LDSTR + s] = vu[i];
        }
    }
    __syncthreads();

    const int w = tid >> 6, lane = tid & 63;
    const int lm = lane & 15, quad = lane >> 4;

    floatx4 acc[4];
    const floatx4 zero = {0.f, 0.f, 0.f, 0.f};
    #pragma unroll
    for (int nt = 0; nt < 4; ++nt) acc[nt] = zero;

    #pragma unroll
    for (int ks = 0; ks < 2; ++ks) {
        short8 av = *reinterpret_cast<const short8*>(
            &Vt[(w * 16 + lm) * LDSTR + ks * 32 + quad * 8]);   // A: rows = dv
        #pragma unroll
        for (int nt = 0; nt < 4; ++nt) {
            short8 bk = *reinterpret_cast<const short8*>(
                &Kt[(nt * 16 + lm) * LDSTR + ks * 32 + quad * 8]);  // B: cols = dk
            acc[nt] = __builtin_amdgcn_mfma_f32_16x16x32_bf16(av, bk, acc[nt], 0, 0, 0);
        }
    }

    float* kvout = KVt + ((size_t)bh * NCHUNK + c) * 4096;
    #pragma unroll
    for (int nt = 0; nt < 4; ++nt)
        #pragma unroll
        for (int r = 0; r < 4; ++r) {
            const int dv = w * 16 + quad * 4 + r;
            const int dk = nt * 16 + lm;
            kvout[dv * 64 + dk] = acc[nt][r];
        }

    if (tid < 64) {
        float s = 0.f;
        #pragma unroll 8
        for (int t = 0; t < 64; ++t) s += bs2f(Kt[tid * LDSTR + t]);
        ksum[((size_t)bh * NCHUNK + c) * 64 + tid] = s;
    }
}

// ---------------------------------------------------------------------------
// Kernel 4: exclusive prefix over chunks — element-parallel (validated r5).
// ---------------------------------------------------------------------------
__global__ __launch_bounds__(256) void prefix_kv(
    float* __restrict__ KVt, float* __restrict__ ksum)
{
    const int bh   = blockIdx.x >> 4;
    const int part = blockIdx.x & 15;
    const int tid  = threadIdx.x;
    const int e    = part * 256 + tid;
    float* base = KVt + (size_t)bh * NCHUNK * 4096 + e;

    float s = 0.f;
    #pragma unroll
    for (int cb = 0; cb < 4; ++cb) {
        float v[16];
        #pragma unroll
        for (int i = 0; i < 16; ++i) v[i] = base[(size_t)(cb * 16 + i) * 4096];
        #pragma unroll
        for (int i = 0; i < 16; ++i) {
            const float tmp = v[i];
            base[(size_t)(cb * 16 + i) * 4096] = s;
            s += tmp;
        }
    }

    if (part == 0 && tid < 64) {
        float* zb = ksum + (size_t)bh * NCHUNK * 64 + tid;
        float z = 0.f;
        #pragma unroll
        for (int cb = 0; cb < 4; ++cb) {
            float v[16];
            #pragma unroll
            for (int i = 0; i < 16; ++i) v[i] = zb[(size_t)(cb * 16 + i) * 64];
            #pragma unroll
            for (int i = 0; i < 16; ++i) {
                const float tmp = v[i];
                zb[(size_t)(cb * 16 + i) * 64] = z;
                z += tmp;
            }
        }
    }
}

// ---------------------------------------------------------------------------
// Kernel 5: per-chunk attention, all-MFMA, registerized den (validated r7).
// ---------------------------------------------------------------------------
__global__ __launch_bounds__(256) void attn_mfma(
    const bf16* __restrict__ Qf, const bf16* __restrict__ Kf,
    const bf16* __restrict__ Vf, const float* __restrict__ KVt,
    const float* __restrict__ ksum, bf16* __restrict__ Of)
{
    const int bh = blockIdx.x >> 6;
    const int c  = blockIdx.x & 63;
    const int b  = bh >> 3, h = bh & 7;

    __shared__ short Qs [64 * LDSTR];  // Q[t][d]
    __shared__ short Ksn[64 * LDSTR];  // K[s][d]
    __shared__ short Vt [64 * LDSTR];  // V^T[dv][s]
    __shared__ short Ps [64 * LDSTR];  // masked scores P[t][s]
    __shared__ short St [64 * LDSTR];  // S_prev^T[dv][dk] (bf16)
    __shared__ float zprev[64];

    const int tid = threadIdx.x;
    const int w = tid >> 6, lane = tid & 63;
    const int lm = lane & 15, quad = lane >> 4;
    const size_t coff = ((size_t)bh * T_SEQ + c * CS) * HD;
    const float* Sp = KVt + ((size_t)bh * NCHUNK + c) * 4096;  // [dv][dk]

    #pragma unroll
    for (int j = 0; j < 2; ++j) {
        const int u  = j * 256 + tid;
        const int e0 = u * 8;
        const int r = e0 >> 6, cc = e0 & 63;
        *reinterpret_cast<short8*>(&Qs [r * LDSTR + cc]) =
            *reinterpret_cast<const short8*>(Qf + coff + e0);
        *reinterpret_cast<short8*>(&Ksn[r * LDSTR + cc]) =
            *reinterpret_cast<const short8*>(Kf + coff + e0);
        short8 vu = *reinterpret_cast<const short8*>(Vf + coff + e0);
        #pragma unroll
        for (int i = 0; i < 8; ++i) Vt[(cc + i) * LDSTR + r] = vu[i];
    }
    // S_prev^T (fp32, [dv][dk]) -> St[dv][dk] bf16: vector loads, 8B stores
    #pragma unroll
    for (int j = 0; j < 4; ++j) {
        const int u  = j * 256 + tid;          // 0..1023 float4
        const int dv = u >> 4, d0 = (u & 15) * 4;
        const float4 s4 = reinterpret_cast<const float4*>(Sp)[u];
        short4v pk;
        pk[0] = f2bs(s4.x); pk[1] = f2bs(s4.y);
        pk[2] = f2bs(s4.z); pk[3] = f2bs(s4.w);
        *reinterpret_cast<short4v*>(&St[dv * LDSTR + d0]) = pk;
    }
    if (tid < 64) zprev[tid] = ksum[((size_t)bh * NCHUNK + c) * 64 + tid];
    __syncthreads();

    const floatx4 zero = {0.f, 0.f, 0.f, 0.f};
    short8 aq[2];
    #pragma unroll
    for (int ks = 0; ks < 2; ++ks)
        aq[ks] = *reinterpret_cast<const short8*>(
            &Qs[(w * 16 + lm) * LDSTR + ks * 32 + quad * 8]);

    // ---- P = Q K^T ----
    floatx4 pacc[4];
    #pragma unroll
    for (int nt = 0; nt < 4; ++nt) pacc[nt] = zero;
    #pragma unroll
    for (int ks = 0; ks < 2; ++ks)
        #pragma unroll
        for (int nt = 0; nt < 4; ++nt) {
            short8 bk = *reinterpret_cast<const short8*>(
                &Ksn[(nt * 16 + lm) * LDSTR + ks * 32 + quad * 8]);
            pacc[nt] = __builtin_amdgcn_mfma_f32_16x16x32_bf16(aq[ks], bk, pacc[nt], 0, 0, 0);
        }

    // mask + write Ps; accumulate per-row sums in registers
    float tot[4] = {0.f, 0.f, 0.f, 0.f};
    #pragma unroll
    for (int nt = 0; nt < 4; ++nt)
        #pragma unroll
        for (int r = 0; r < 4; ++r) {
            const int t = w * 16 + quad * 4 + r;
            const int s = nt * 16 + lm;
            const float m = (s <= t) ? pacc[nt][r] : 0.f;
            Ps[t * LDSTR + s] = f2bs(m);
            tot[r] += m;
        }
    // + q.z partials: lane lm covers d = lm, lm+16, lm+32, lm+48
    #pragma unroll
    for (int r = 0; r < 4; ++r) {
        const int t = w * 16 + quad * 4 + r;
        #pragma unroll
        for (int j = 0; j < 4; ++j) {
            const int d = lm + j * 16;
            tot[r] += bs2f(Qs[t * LDSTR + d]) * zprev[d];
        }
    }
    #pragma unroll
    for (int mask = 1; mask < 16; mask <<= 1)
        #pragma unroll
        for (int r = 0; r < 4; ++r) tot[r] += __shfl_xor(tot[r], mask);
    float rdenl[4];
    #pragma unroll
    for (int r = 0; r < 4; ++r) rdenl[r] = 1.f / (tot[r] + 1e-6f);

    // ---- O = Q @ S_prev^T (MFMA) ----
    floatx4 oacc[4];
    #pragma unroll
    for (int nt = 0; nt < 4; ++nt) oacc[nt] = zero;
    #pragma unroll
    for (int ks = 0; ks < 2; ++ks)
        #pragma unroll
        for (int nt = 0; nt < 4; ++nt) {
            short8 bs = *reinterpret_cast<const short8*>(
                &St[(nt * 16 + lm) * LDSTR + ks * 32 + quad * 8]);
            oacc[nt] = __builtin_amdgcn_mfma_f32_16x16x32_bf16(aq[ks], bs, oacc[nt], 0, 0, 0);
        }
    __syncthreads();   // Ps complete

    // ---- O += P V ----
    #pragma unroll
    for (int ks = 0; ks < 2; ++ks) {
        short8 ap = *reinterpret_cast<const short8*>(
            &Ps[(w * 16 + lm) * LDSTR + ks * 32 + quad * 8]);
        #pragma unroll
        for (int nt = 0; nt < 4; ++nt) {
            short8 bv = *reinterpret_cast<const short8*>(
                &Vt[(nt * 16 + lm) * LDSTR + ks * 32 + quad * 8]);
            oacc[nt] = __builtin_amdgcn_mfma_f32_16x16x32_bf16(ap, bv, oacc[nt], 0, 0, 0);
        }
    }

    #pragma unroll
    for (int nt = 0; nt < 4; ++nt)
        #pragma unroll
        for (int r = 0; r < 4; ++r) {
            const int t  = w * 16 + quad * 4 + r;
            const int dv = nt * 16 + lm;
            const int tg = c * CS + t;
            Of[((size_t)(b * T_SEQ + tg)) * EMB + h * HD + dv] =
                __float2bfloat16(oacc[nt][r] * rdenl[r]);
        }
}

// ---------------------------------------------------------------------------
// Kernel 6: output projection — LDS-free direct-fragment GEMM, self-probing
// store dtype.  out = Of @ Wo^T + bo.  Grid (64, 4).
// ---------------------------------------------------------------------------
__global__ __launch_bounds__(256) void out_proj_direct(
    const void* __restrict__ xprobe,
    const short* __restrict__ A, const short* __restrict__ Wb,
    const short* __restrict__ bb, void* __restrict__ out)
{
    const int mode = probe_mode(xprobe);

    const int mbase = blockIdx.x * 128;
    const int nbase = blockIdx.y * 128;
    const short* W = Wb + (size_t)3 * 262144;
    const bf16* bias = (const bf16*)(bb + 3 * 512);

    const int tid  = threadIdx.x;
    const int wave = tid >> 6, lane = tid & 63;
    const int wm = wave >> 1, wn = wave & 1;
    const int lm = lane & 15, quad = lane >> 4;

    const size_t abase = (size_t)(mbase + wm * 64 + lm) * EMB + quad * 8;
    const size_t bbase = (size_t)(nbase + wn * 64 + lm) * EMB + quad * 8;

    floatx4 acc[4][4];
    const floatx4 zero = {0.f, 0.f, 0.f, 0.f};
    #pragma unroll
    for (int mt = 0; mt < 4; ++mt)
        #pragma unroll
        for (int nt = 0; nt < 4; ++nt) acc[mt][nt] = zero;

    for (int kt = 0; kt < EMB; kt += 64) {
        short8 af[4][2], bf[4][2];
        #pragma unroll
        for (int mt = 0; mt < 4; ++mt)
            #pragma unroll
            for (int ks = 0; ks < 2; ++ks)
                af[mt][ks] = *reinterpret_cast<const short8*>(
                    A + abase + (size_t)mt * 16 * EMB + kt + ks * 32);
        #pragma unroll
        for (int nt = 0; nt < 4; ++nt)
            #pragma unroll
            for (int ks = 0; ks < 2; ++ks)
                bf[nt][ks] = *reinterpret_cast<const short8*>(
                    W + bbase + (size_t)nt * 16 * EMB + kt + ks * 32);
        #pragma unroll
        for (int ks = 0; ks < 2; ++ks)
            #pragma unroll
            for (int mt = 0; mt < 4; ++mt)
                #pragma unroll
                for (int nt = 0; nt < 4; ++nt)
                    acc[mt][nt] = __builtin_amdgcn_mfma_f32_16x16x32_bf16(
                        af[mt][ks], bf[nt][ks], acc[mt][nt], 0, 0, 0);
    }

    #pragma unroll
    for (int nt = 0; nt < 4; ++nt) {
        const int col = nbase + wn * 64 + nt * 16 + lm;
        const float bv_ = load_elem(bias, col);
        #pragma unroll
        for (int mt = 0; mt < 4; ++mt)
            #pragma unroll
            for (int r = 0; r < 4; ++r) {
                const int row = mbase + wm * 64 + mt * 16 + quad * 4 + r;
                const float v = acc[mt][nt][r] + bv_;
                if (mode) ((float*)out)[(size_t)row * EMB + col] = v;
                else      ((bf16*)out)[(size_t)row * EMB + col] = __float2bfloat16(v);
            }
    }
}

// ---------------------------------------------------------------------------
extern "C" void kernel_launch(void* const* d_in, const int* in_sizes, int n_in,
                              void* d_out, int out_size, void* d_ws, size_t ws_size,
                              hipStream_t stream)
{
    // workspace (~50.3 MB):
    //   reserved 64 B
    //   Qf/Kf/Vf : bf16 4,194,304 each                (24 MB)
    //   union  : [ KVt fp32 4,194,304 | xb bf16 4,194,304 ]  (16 MB)
    //   ksum   : fp32 65,536                           (0.25 MB)
    //   Of     : bf16 4,194,304                        (8 MB)
    //   Wb     : bf16 4x262,144                        (2 MB)
    //   bb     : bf16 4x512                            (4 KB)
    bf16* Qf = (bf16*)((char*)d_ws + 64);
    bf16* Kf = Qf + 4194304;
    bf16* Vf = Kf + 4194304;
    float* KVt = (float*)(Vf + 4194304);
    short* xb = (short*)KVt;                // aliased (disjoint lifetime)
    float* ks = KVt + 4194304;
    bf16* Of = (bf16*)(ks + 65536);
    short* Wb = (short*)(Of + 4194304);
    short* bb = Wb + 1048576;

    convert_all<<<dim3(2561), 256, 0, stream>>>(
        d_in[0], d_in[1], d_in[2], d_in[3], d_in[4],
        d_in[5], d_in[6], d_in[7], d_in[8], xb, Wb, bb);

    qkv_direct<<<dim3(64, 12), 256, 0, stream>>>(xb, Wb, bb, Qf, Kf, Vf);
    chunk_kv<<<dim3(BHEADS * NCHUNK), 256, 0, stream>>>(Kf, Vf, KVt, ks);
    prefix_kv<<<dim3(BHEADS * 16), 256, 0, stream>>>(KVt, ks);
    attn_mfma<<<dim3(BHEADS * NCHUNK), 256, 0, stream>>>(Qf, Kf, Vf, KVt, ks, Of);

    out_proj_direct<<<dim3(64, 4), 256, 0, stream>>>(
        d_in[0], (const short*)Of, Wb, bb, d_out);
}

// Round 9
// 164.746 us; speedup vs baseline: 1.1391x; 1.1391x over previous
//
#include <hip/hip_runtime.h>
#include <hip/hip_bf16.h>

// Problem constants: B=2, T=4096, E=512, H=8, D=64
#define T_SEQ 4096
#define EMB   512
#define NH    8
#define HD    64
#define BATCH 2
#define M_ROWS (BATCH * T_SEQ)   // 8192
#define NCHUNK 64                // T / CS
#define CS     64                // chunk size
#define BHEADS (BATCH * NH)      // 16

using bf16 = __hip_bfloat16;
typedef __attribute__((ext_vector_type(8))) short short8;   // 8 bf16 = 4 VGPR
typedef __attribute__((ext_vector_type(4))) float floatx4;  // MFMA acc

__device__ __forceinline__ float bs2f(short s) {
    return __uint_as_float(((unsigned)(unsigned short)s) << 16);
}
__device__ __forceinline__ short f2bs(float f) {
    bf16 h = __float2bfloat16(f);
    return *reinterpret_cast<short*>(&h);
}
__device__ __forceinline__ float load_elem(const bf16* p, size_t i) {
    return __bfloat162float(p[i]);
}
// convert 8 consecutive elems (any dtype) -> bf16, 16B write
__device__ __forceinline__ void stage8(const bf16* g, short* l) {
    *reinterpret_cast<short8*>(l) = *reinterpret_cast<const short8*>(g);
}
__device__ __forceinline__ void stage8(const float* g, short* l) {
    float4 a = *reinterpret_cast<const float4*>(g);
    float4 b = *reinterpret_cast<const float4*>(g + 4);
    short8 v;
    v[0] = f2bs(a.x); v[1] = f2bs(a.y); v[2] = f2bs(a.z); v[3] = f2bs(a.w);
    v[4] = f2bs(b.x); v[5] = f2bs(b.y); v[6] = f2bs(b.z); v[7] = f2bs(b.w);
    *reinterpret_cast<short8*>(l) = v;
}

// async global->LDS: each lane copies 16B to (wave-uniform base) + lane*16
__device__ __forceinline__ void gload_lds16(const short* g, short* l) {
    __builtin_amdgcn_global_load_lds(
        (const __attribute__((address_space(1))) void*)g,
        (__attribute__((address_space(3))) void*)l, 16, 0, 0);
}

#define LDSTR 72   // padded LDS row stride (shorts) for transposed tiles

// ---------------------------------------------------------------------------
// In-block dtype probe (validated r7).  1 = fp32, 0 = bf16.  256 threads.
// ---------------------------------------------------------------------------
__device__ __forceinline__ int probe_mode(const void* x) {
    const uint4* p = (const uint4*)x;
    const int tid = threadIdx.x;
    bool bad = false;
    #pragma unroll
    for (int i = 0; i < 2; ++i) {
        uint4 u = p[tid + i * 256];
        const unsigned w[4] = {u.x, u.y, u.z, u.w};
        #pragma unroll
        for (int k = 0; k < 4; ++k) {
            const float f = __uint_as_float(w[k] << 16);   // low half
            if (!(fabsf(f) <= 1e9f)) bad = true;
        }
    }
    return __syncthreads_or(bad ? 1 : 0) ? 1 : 0;
}

// ---------------------------------------------------------------------------
// Kernel 1: convert x, Wq/Wk/Wv/Wo, biases -> bf16 ws (validated r7).
// ---------------------------------------------------------------------------
template <typename T>
__device__ __forceinline__ void convert_body(
    const void* const* in, short* xb, short* Wb, short* bb, int c)
{
    if (c < 524288) {
        stage8((const T*)in[0] + (size_t)c * 8, xb + (size_t)c * 8);
    } else if (c < 655360) {
        const int c2 = c - 524288;
        const int w = c2 >> 15;             // 0..3 : Wq Wk Wv Wo
        const int off = (c2 & 32767) * 8;
        const T* src = (const T*)in[w == 0 ? 1 : (w == 1 ? 3 : (w == 2 ? 5 : 7))];
        stage8(src + off, Wb + w * 262144 + off);
    } else if (c < 655616) {
        const int c3 = c - 655360;          // 0..255
        const int bsel = c3 >> 6;
        const int off = (c3 & 63) * 8;
        const T* src = (const T*)in[bsel == 0 ? 2 : (bsel == 1 ? 4 : (bsel == 2 ? 6 : 8))];
        stage8(src + off, bb + bsel * 512 + off);
    }
}

__global__ __launch_bounds__(256) void convert_all(
    const void* x, const void* Wq, const void* bq,
    const void* Wk, const void* bk, const void* Wv, const void* bv,
    const void* Wo, const void* bo,
    short* __restrict__ xb, short* __restrict__ Wb, short* __restrict__ bb)
{
    const void* in[9] = {x, Wq, bq, Wk, bk, Wv, bv, Wo, bo};
    const int mode = probe_mode(x);
    const int c = blockIdx.x * 256 + threadIdx.x;
    if (mode) convert_body<float>(in, xb, Wb, bb, c);
    else      convert_body<bf16>(in, xb, Wb, bb, c);
}

// ---------------------------------------------------------------------------
// Kernel 2: fused QKV projection via gload_lds (REVERTED to validated r7 —
// r8's direct-fragment loop serialized at VGPR=68 and regressed).
// ---------------------------------------------------------------------------
__global__ __launch_bounds__(256) void qkv_gemm_dl(
    const short* __restrict__ xb, const short* __restrict__ Wb,
    const short* __restrict__ bb,
    bf16* __restrict__ Qf, bf16* __restrict__ Kf, bf16* __restrict__ Vf)
{
    const int mtile = blockIdx.x;            // 0..63
    const int ntile = blockIdx.y;            // 0..11
    const int which = ntile >> 2;
    const short* W = Wb + (size_t)which * 262144;
    const bf16* bias = (const bf16*)(bb + which * 512);
    bf16* outp = (which == 0) ? Qf : ((which == 1) ? Kf : Vf);
    const int nbase = (ntile & 3) * 128;
    const int mbase = mtile * 128;

    __shared__ short As[128 * 64];   // packed: row stride 64 shorts
    __shared__ short Bs[128 * 64];

    const int tid  = threadIdx.x;
    const int wave = tid >> 6, lane = tid & 63;
    const int wm = wave >> 1, wn = wave & 1;
    const int lm = lane & 15, quad = lane >> 4;
    const int srow = lane >> 3;           // 0..7 within issue
    const int scol = (lane & 7) * 8;      // 0,8,..,56

    floatx4 acc[4][4];
    const floatx4 zero = {0.f, 0.f, 0.f, 0.f};
    #pragma unroll
    for (int mt = 0; mt < 4; ++mt)
        #pragma unroll
        for (int nt = 0; nt < 4; ++nt) acc[mt][nt] = zero;

    for (int kt = 0; kt < EMB; kt += 64) {
        #pragma unroll
        for (int j = 0; j < 4; ++j) {
            const int issue = wave * 4 + j;          // 0..15, 8 rows each
            const int row = issue * 8 + srow;
            gload_lds16(xb + (size_t)(mbase + row) * EMB + kt + scol,
                        &As[issue * 512]);
            gload_lds16(W  + (size_t)(nbase + row) * EMB + kt + scol,
                        &Bs[issue * 512]);
        }
        __syncthreads();
        #pragma unroll
        for (int ks = 0; ks < 2; ++ks) {
            short8 af[4], bfr[4];
            #pragma unroll
            for (int mt = 0; mt < 4; ++mt)
                af[mt] = *reinterpret_cast<const short8*>(
                    &As[(wm * 64 + mt * 16 + lm) * 64 + ks * 32 + quad * 8]);
            #pragma unroll
            for (int nt = 0; nt < 4; ++nt)
                bfr[nt] = *reinterpret_cast<const short8*>(
                    &Bs[(wn * 64 + nt * 16 + lm) * 64 + ks * 32 + quad * 8]);
            #pragma unroll
            for (int mt = 0; mt < 4; ++mt)
                #pragma unroll
                for (int nt = 0; nt < 4; ++nt)
                    acc[mt][nt] = __builtin_amdgcn_mfma_f32_16x16x32_bf16(
                        af[mt], bfr[nt], acc[mt][nt], 0, 0, 0);
        }
        __syncthreads();
    }

    #pragma unroll
    for (int nt = 0; nt < 4; ++nt) {
        const int col = nbase + wn * 64 + nt * 16 + lm;   // 0..511
        const float bv_ = load_elem(bias, col & 511);
        const int h = col >> 6, d = col & 63;
        #pragma unroll
        for (int mt = 0; mt < 4; ++mt)
            #pragma unroll
            for (int r = 0; r < 4; ++r) {
                const int row = mbase + wm * 64 + mt * 16 + quad * 4 + r;
                const int b = row >> 12, t = row & (T_SEQ - 1);
                float v = acc[mt][nt][r] + bv_;
                if (which != 2) v = (v > 0.f) ? (v + 1.f) : __expf(v);  // elu+1
                outp[(((size_t)(b * NH + h)) * T_SEQ + t) * HD + d] = __float2bfloat16(v);
            }
    }
}

// ---------------------------------------------------------------------------
// Kernel 3: per-chunk (K^T V)^T via MFMA + k column sums + V^T tile export.
// Writes KV increments as bf16 [dv][dk] (state is bf16 at use since r6) and
// the V^T tile (already built in LDS) so attn never transposes.  1024 blocks.
// ---------------------------------------------------------------------------
__global__ __launch_bounds__(256) void chunk_kv(
    const bf16* __restrict__ Kf, const bf16* __restrict__ Vf,
    short* __restrict__ KVc, float* __restrict__ ksum,
    short* __restrict__ Vtg)
{
    const int bh = blockIdx.x >> 6;
    const int c  = blockIdx.x & 63;
    __shared__ short Kt[64 * LDSTR];   // Kt[dk][s]
    __shared__ short Vt[64 * LDSTR];   // Vt[dv][s]
    const int tid = threadIdx.x;
    const bf16* kp = Kf + ((size_t)bh * T_SEQ + c * CS) * HD;
    const bf16* vp = Vf + ((size_t)bh * T_SEQ + c * CS) * HD;
    const size_t toff = ((size_t)bh * NCHUNK + c) * 4096;

    #pragma unroll
    for (int j = 0; j < 2; ++j) {
        const int u = j * 256 + tid;
        const int e0 = u * 8;
        const int s = e0 >> 6, d0 = e0 & 63;
        short8 ku = *reinterpret_cast<const short8*>(kp + e0);
        short8 vu = *reinterpret_cast<const short8*>(vp + e0);
        #pragma unroll
        for (int i = 0; i < 8; ++i) {
            Kt[(d0 + i) * LDSTR + s] = ku[i];
            Vt[(d0 + i) * LDSTR + s] = vu[i];
        }
    }
    __syncthreads();

    // export V^T tile: packed [dv][s] stride 64, coalesced 16B stores
    #pragma unroll
    for (int j = 0; j < 2; ++j) {
        const int u = j * 256 + tid;
        const int e0 = u * 8;
        const int row = e0 >> 6, col = e0 & 63;
        *reinterpret_cast<short8*>(Vtg + toff + row * 64 + col) =
            *reinterpret_cast<const short8*>(&Vt[row * LDSTR + col]);
    }

    const int w = tid >> 6, lane = tid & 63;
    const int lm = lane & 15, quad = lane >> 4;

    floatx4 acc[4];
    const floatx4 zero = {0.f, 0.f, 0.f, 0.f};
    #pragma unroll
    for (int nt = 0; nt < 4; ++nt) acc[nt] = zero;

    #pragma unroll
    for (int ks = 0; ks < 2; ++ks) {
        short8 av = *reinterpret_cast<const short8*>(
            &Vt[(w * 16 + lm) * LDSTR + ks * 32 + quad * 8]);   // A: rows = dv
        #pragma unroll
        for (int nt = 0; nt < 4; ++nt) {
            short8 bk = *reinterpret_cast<const short8*>(
                &Kt[(nt * 16 + lm) * LDSTR + ks * 32 + quad * 8]);  // B: cols = dk
            acc[nt] = __builtin_amdgcn_mfma_f32_16x16x32_bf16(av, bk, acc[nt], 0, 0, 0);
        }
    }

    #pragma unroll
    for (int nt = 0; nt < 4; ++nt)
        #pragma unroll
        for (int r = 0; r < 4; ++r) {
            const int dv = w * 16 + quad * 4 + r;
            const int dk = nt * 16 + lm;
            KVc[toff + dv * 64 + dk] = f2bs(acc[nt][r]);
        }

    if (tid < 64) {
        float s = 0.f;
        #pragma unroll 8
        for (int t = 0; t < 64; ++t) s += bs2f(Kt[tid * LDSTR + t]);
        ksum[((size_t)bh * NCHUNK + c) * 64 + tid] = s;
    }
}

// ---------------------------------------------------------------------------
// Kernel 4: exclusive prefix over chunks — element-parallel register scan,
// bf16 in-place (scan accumulates in fp32 registers).  256 blocks.
// ---------------------------------------------------------------------------
__global__ __launch_bounds__(256) void prefix_kv(
    short* __restrict__ KVc, float* __restrict__ ksum)
{
    const int bh   = blockIdx.x >> 4;
    const int part = blockIdx.x & 15;
    const int tid  = threadIdx.x;
    const int e    = part * 256 + tid;
    short* base = KVc + (size_t)bh * NCHUNK * 4096 + e;

    float s = 0.f;
    #pragma unroll
    for (int cb = 0; cb < 4; ++cb) {
        float v[16];
        #pragma unroll
        for (int i = 0; i < 16; ++i) v[i] = bs2f(base[(size_t)(cb * 16 + i) * 4096]);
        #pragma unroll
        for (int i = 0; i < 16; ++i) {
            const float tmp = v[i];
            base[(size_t)(cb * 16 + i) * 4096] = f2bs(s);
            s += tmp;
        }
    }

    if (part == 0 && tid < 64) {
        float* zb = ksum + (size_t)bh * NCHUNK * 64 + tid;
        float z = 0.f;
        #pragma unroll
        for (int cb = 0; cb < 4; ++cb) {
            float v[16];
            #pragma unroll
            for (int i = 0; i < 16; ++i) v[i] = zb[(size_t)(cb * 16 + i) * 64];
            #pragma unroll
            for (int i = 0; i < 16; ++i) {
                const float tmp = v[i];
                zb[(size_t)(cb * 16 + i) * 64] = z;
                z += tmp;
            }
        }
    }
}

// ---------------------------------------------------------------------------
// Kernel 5: per-chunk attention — barrier-free, direct-fragment loads.
// All operand fragments (Q, K, S^T, V^T) load straight from global, issued
// once up-front (no loop -> no r8 latency trap).  Only P round-trips through
// LDS, and its rows are wave-local -> NO __syncthreads.  den registerized.
// ---------------------------------------------------------------------------
__global__ __launch_bounds__(256) void attn_lite(
    const bf16* __restrict__ Qf, const bf16* __restrict__ Kf,
    const short* __restrict__ Vtg, const short* __restrict__ KVc,
    const float* __restrict__ ksum, bf16* __restrict__ Of)
{
    const int bh = blockIdx.x >> 6;
    const int c  = blockIdx.x & 63;
    const int b  = bh >> 3, h = bh & 7;

    __shared__ short Ps[64 * LDSTR];   // masked scores P[t][s]
    __shared__ float qzbuf[64];        // q.z per row

    const int tid = threadIdx.x;
    const int w = tid >> 6, lane = tid & 63;
    const int lm = lane & 15, quad = lane >> 4;
    const size_t coff = ((size_t)bh * T_SEQ + c * CS) * HD;
    const size_t toff = ((size_t)bh * NCHUNK + c) * 4096;   // tile base

    // ---- A-fragments of Q (row w*16+lm), direct from global ----
    short8 aq[2];
    #pragma unroll
    for (int ks = 0; ks < 2; ++ks)
        aq[ks] = *reinterpret_cast<const short8*>(
            Qf + coff + (w * 16 + lm) * HD + ks * 32 + quad * 8);

    // ---- q.z partials: lane holds Q[w*16+lm][ks*32+quad*8+j] ----
    const float* zp = ksum + ((size_t)bh * NCHUNK + c) * 64;
    float qz = 0.f;
    #pragma unroll
    for (int ks = 0; ks < 2; ++ks) {
        const float4 z0 = *reinterpret_cast<const float4*>(zp + ks * 32 + quad * 8);
        const float4 z1 = *reinterpret_cast<const float4*>(zp + ks * 32 + quad * 8 + 4);
        qz += bs2f(aq[ks][0]) * z0.x + bs2f(aq[ks][1]) * z0.y
            + bs2f(aq[ks][2]) * z0.z + bs2f(aq[ks][3]) * z0.w
            + bs2f(aq[ks][4]) * z1.x + bs2f(aq[ks][5]) * z1.y
            + bs2f(aq[ks][6]) * z1.z + bs2f(aq[ks][7]) * z1.w;
    }
    qz += __shfl_xor(qz, 16);
    qz += __shfl_xor(qz, 32);          // all 4 quads now hold full q.z of row lm
    if (quad == 0) qzbuf[w * 16 + lm] = qz;   // wave-local write

    // ---- P = Q K^T (K B-frags direct from global, row-major k=d) ----
    const floatx4 zero = {0.f, 0.f, 0.f, 0.f};
    floatx4 pacc[4];
    #pragma unroll
    for (int nt = 0; nt < 4; ++nt) pacc[nt] = zero;
    #pragma unroll
    for (int ks = 0; ks < 2; ++ks)
        #pragma unroll
        for (int nt = 0; nt < 4; ++nt) {
            short8 bk = *reinterpret_cast<const short8*>(
                Kf + coff + (nt * 16 + lm) * HD + ks * 32 + quad * 8);
            pacc[nt] = __builtin_amdgcn_mfma_f32_16x16x32_bf16(aq[ks], bk, pacc[nt], 0, 0, 0);
        }

    // mask + write Ps (wave-local rows) + register rowsums
    float tot[4] = {0.f, 0.f, 0.f, 0.f};
    #pragma unroll
    for (int nt = 0; nt < 4; ++nt)
        #pragma unroll
        for (int r = 0; r < 4; ++r) {
            const int t = w * 16 + quad * 4 + r;
            const int s = nt * 16 + lm;
            const float m = (s <= t) ? pacc[nt][r] : 0.f;
            Ps[t * LDSTR + s] = f2bs(m);
            tot[r] += m;
        }
    #pragma unroll
    for (int mask = 1; mask < 16; mask <<= 1)
        #pragma unroll
        for (int r = 0; r < 4; ++r) tot[r] += __shfl_xor(tot[r], mask);

    // ---- O = Q @ S_prev^T (S^T tile bf16, direct B-frags) ----
    floatx4 oacc[4];
    #pragma unroll
    for (int nt = 0; nt < 4; ++nt) oacc[nt] = zero;
    #pragma unroll
    for (int ks = 0; ks < 2; ++ks)
        #pragma unroll
        for (int nt = 0; nt < 4; ++nt) {
            short8 bs = *reinterpret_cast<const short8*>(
                KVc + toff + (nt * 16 + lm) * 64 + ks * 32 + quad * 8);
            oacc[nt] = __builtin_amdgcn_mfma_f32_16x16x32_bf16(aq[ks], bs, oacc[nt], 0, 0, 0);
        }

    // ---- O += P V (P A-frags from own wave's Ps rows; V^T direct) ----
    #pragma unroll
    for (int ks = 0; ks < 2; ++ks) {
        short8 ap = *reinterpret_cast<const short8*>(
            &Ps[(w * 16 + lm) * LDSTR + ks * 32 + quad * 8]);
        #pragma unroll
        for (int nt = 0; nt < 4; ++nt) {
            short8 bv = *reinterpret_cast<const short8*>(
                Vtg + toff + (nt * 16 + lm) * 64 + ks * 32 + quad * 8);
            oacc[nt] = __builtin_amdgcn_mfma_f32_16x16x32_bf16(ap, bv, oacc[nt], 0, 0, 0);
        }
    }

    // ---- denominator + store ----
    float rdenl[4];
    #pragma unroll
    for (int r = 0; r < 4; ++r)
        rdenl[r] = 1.f / (tot[r] + qzbuf[w * 16 + quad * 4 + r] + 1e-6f);

    #pragma unroll
    for (int nt = 0; nt < 4; ++nt)
        #pragma unroll
        for (int r = 0; r < 4; ++r) {
            const int t  = w * 16 + quad * 4 + r;
            const int dv = nt * 16 + lm;
            const int tg = c * CS + t;
            Of[((size_t)(b * T_SEQ + tg)) * EMB + h * HD + dv] =
                __float2bfloat16(oacc[nt][r] * rdenl[r]);
        }
}

// ---------------------------------------------------------------------------
// Kernel 6: output projection via gload_lds (REVERTED to validated r7),
// self-probing store dtype.  out = Of @ Wo^T + bo.  Grid (64, 4).
// ---------------------------------------------------------------------------
__global__ __launch_bounds__(256) void out_proj_dl(
    const void* __restrict__ xprobe,
    const short* __restrict__ A, const short* __restrict__ Wb,
    const short* __restrict__ bb, void* __restrict__ out)
{
    const int mode = probe_mode(xprobe);

    const int mbase = blockIdx.x * 128;
    const int nbase = blockIdx.y * 128;
    const short* W = Wb + (size_t)3 * 262144;
    const bf16* bias = (const bf16*)(bb + 3 * 512);

    __shared__ short As[128 * 64];
    __shared__ short Bs[128 * 64];

    const int tid  = threadIdx.x;
    const int wave = tid >> 6, lane = tid & 63;
    const int wm = wave >> 1, wn = wave & 1;
    const int lm = lane & 15, quad = lane >> 4;
    const int srow = lane >> 3;
    const int scol = (lane & 7) * 8;

    floatx4 acc[4][4];
    const floatx4 zero = {0.f, 0.f, 0.f, 0.f};
    #pragma unroll
    for (int mt = 0; mt < 4; ++mt)
        #pragma unroll
        for (int nt = 0; nt < 4; ++nt) acc[mt][nt] = zero;

    for (int kt = 0; kt < EMB; kt += 64) {
        #pragma unroll
        for (int j = 0; j < 4; ++j) {
            const int issue = wave * 4 + j;
            const int row = issue * 8 + srow;
            gload_lds16(A + (size_t)(mbase + row) * EMB + kt + scol,
                        &As[issue * 512]);
            gload_lds16(W + (size_t)(nbase + row) * EMB + kt + scol,
                        &Bs[issue * 512]);
        }
        __syncthreads();
        #pragma unroll
        for (int ks = 0; ks < 2; ++ks) {
            short8 af[4], bfr[4];
            #pragma unroll
            for (int mt = 0; mt < 4; ++mt)
                af[mt] = *reinterpret_cast<const short8*>(
                    &As[(wm * 64 + mt * 16 + lm) * 64 + ks * 32 + quad * 8]);
            #pragma unroll
            for (int nt = 0; nt < 4; ++nt)
                bfr[nt] = *reinterpret_cast<const short8*>(
                    &Bs[(wn * 64 + nt * 16 + lm) * 64 + ks * 32 + quad * 8]);
            #pragma unroll
            for (int mt = 0; mt < 4; ++mt)
                #pragma unroll
                for (int nt = 0; nt < 4; ++nt)
                    acc[mt][nt] = __builtin_amdgcn_mfma_f32_16x16x32_bf16(
                        af[mt], bfr[nt], acc[mt][nt], 0, 0, 0);
        }
        __syncthreads();
    }

    #pragma unroll
    for (int nt = 0; nt < 4; ++nt) {
        const int col = nbase + wn * 64 + nt * 16 + lm;
        const float bv_ = load_elem(bias, col);
        #pragma unroll
        for (int mt = 0; mt < 4; ++mt)
            #pragma unroll
            for (int r = 0; r < 4; ++r) {
                const int row = mbase + wm * 64 + mt * 16 + quad * 4 + r;
                const float v = acc[mt][nt][r] + bv_;
                if (mode) ((float*)out)[(size_t)row * EMB + col] = v;
                else      ((bf16*)out)[(size_t)row * EMB + col] = __float2bfloat16(v);
            }
    }
}

// ---------------------------------------------------------------------------
extern "C" void kernel_launch(void* const* d_in, const int* in_sizes, int n_in,
                              void* d_out, int out_size, void* d_ws, size_t ws_size,
                              hipStream_t stream)
{
    // workspace (~58.3 MB):
    //   reserved 64 B
    //   Qf/Kf/Vf : bf16 4,194,304 each                    (24 MB)
    //   union  : [ KVc bf16 4,194,304 | xb bf16 4,194,304 ]  (8 MB)
    //            xb live: convert->qkv; KVc live: chunk->attn (disjoint)
    //   ksum   : fp32 65,536                               (0.25 MB)
    //   Of     : bf16 4,194,304                            (8 MB)
    //   Wb     : bf16 4x262,144                            (2 MB)
    //   bb     : bf16 4x512                                (4 KB)
    //   Vtg    : bf16 4,194,304 (V^T tiles)                (8 MB)
    bf16* Qf = (bf16*)((char*)d_ws + 64);
    bf16* Kf = Qf + 4194304;
    bf16* Vf = Kf + 4194304;
    short* KVc = (short*)(Vf + 4194304);
    short* xb = KVc;                        // aliased (disjoint lifetime)
    float* ks = (float*)(KVc + 4194304);
    bf16* Of = (bf16*)(ks + 65536);
    short* Wb = (short*)(Of + 4194304);
    short* bb = Wb + 1048576;
    short* Vtg = bb + 2048;

    convert_all<<<dim3(2561), 256, 0, stream>>>(
        d_in[0], d_in[1], d_in[2], d_in[3], d_in[4],
        d_in[5], d_in[6], d_in[7], d_in[8], xb, Wb, bb);

    qkv_gemm_dl<<<dim3(64, 12), 256, 0, stream>>>(xb, Wb, bb, Qf, Kf, Vf);
    chunk_kv<<<dim3(BHEADS * NCHUNK), 256, 0, stream>>>(Kf, Vf, KVc, ks, Vtg);
    prefix_kv<<<dim3(BHEADS * 16), 256, 0, stream>>>(KVc, ks);
    attn_lite<<<dim3(BHEADS * NCHUNK), 256, 0, stream>>>(Qf, Kf, Vtg, KVc, ks, Of);

    out_proj_dl<<<dim3(64, 4), 256, 0, stream>>>(
        d_in[0], (const short*)Of, Wb, bb, d_out);
}

// Round 10
// 162.241 us; speedup vs baseline: 1.1567x; 1.0154x over previous
//
#include <hip/hip_runtime.h>
#include <hip/hip_bf16.h>

// Problem constants: B=2, T=4096, E=512, H=8, D=64
#define T_SEQ 4096
#define EMB   512
#define NH    8
#define HD    64
#define BATCH 2
#define M_ROWS (BATCH * T_SEQ)   // 8192
#define NCHUNK 64                // T / CS
#define CS     64                // chunk size
#define BHEADS (BATCH * NH)      // 16

using bf16 = __hip_bfloat16;
typedef __attribute__((ext_vector_type(8))) short short8;   // 8 bf16 = 4 VGPR
typedef __attribute__((ext_vector_type(4))) float floatx4;  // MFMA acc

__device__ __forceinline__ float bs2f(short s) {
    return __uint_as_float(((unsigned)(unsigned short)s) << 16);
}
__device__ __forceinline__ short f2bs(float f) {
    bf16 h = __float2bfloat16(f);
    return *reinterpret_cast<short*>(&h);
}
__device__ __forceinline__ float load_elem(const bf16* p, size_t i) {
    return __bfloat162float(p[i]);
}
// convert 8 consecutive elems (any dtype) -> bf16, 16B write
__device__ __forceinline__ void stage8(const bf16* g, short* l) {
    *reinterpret_cast<short8*>(l) = *reinterpret_cast<const short8*>(g);
}
__device__ __forceinline__ void stage8(const float* g, short* l) {
    float4 a = *reinterpret_cast<const float4*>(g);
    float4 b = *reinterpret_cast<const float4*>(g + 4);
    short8 v;
    v[0] = f2bs(a.x); v[1] = f2bs(a.y); v[2] = f2bs(a.z); v[3] = f2bs(a.w);
    v[4] = f2bs(b.x); v[5] = f2bs(b.y); v[6] = f2bs(b.z); v[7] = f2bs(b.w);
    *reinterpret_cast<short8*>(l) = v;
}

// async global->LDS: each lane copies 16B to (wave-uniform base) + lane*16
__device__ __forceinline__ void gload_lds16(const short* g, short* l) {
    __builtin_amdgcn_global_load_lds(
        (const __attribute__((address_space(1))) void*)g,
        (__attribute__((address_space(3))) void*)l, 16, 0, 0);
}

#define LDSTR 72   // padded LDS row stride (shorts) for transposed tiles

// ---------------------------------------------------------------------------
// In-block dtype probe (validated r7).  1 = fp32, 0 = bf16.  256 threads.
// ---------------------------------------------------------------------------
__device__ __forceinline__ int probe_mode(const void* x) {
    const uint4* p = (const uint4*)x;
    const int tid = threadIdx.x;
    bool bad = false;
    #pragma unroll
    for (int i = 0; i < 2; ++i) {
        uint4 u = p[tid + i * 256];
        const unsigned w[4] = {u.x, u.y, u.z, u.w};
        #pragma unroll
        for (int k = 0; k < 4; ++k) {
            const float f = __uint_as_float(w[k] << 16);   // low half
            if (!(fabsf(f) <= 1e9f)) bad = true;
        }
    }
    return __syncthreads_or(bad ? 1 : 0) ? 1 : 0;
}

// ---------------------------------------------------------------------------
// Kernel 1: convert x, Wq/Wk/Wv/Wo, biases -> bf16 ws (validated r7).
// ---------------------------------------------------------------------------
template <typename T>
__device__ __forceinline__ void convert_body(
    const void* const* in, short* xb, short* Wb, short* bb, int c)
{
    if (c < 524288) {
        stage8((const T*)in[0] + (size_t)c * 8, xb + (size_t)c * 8);
    } else if (c < 655360) {
        const int c2 = c - 524288;
        const int w = c2 >> 15;             // 0..3 : Wq Wk Wv Wo
        const int off = (c2 & 32767) * 8;
        const T* src = (const T*)in[w == 0 ? 1 : (w == 1 ? 3 : (w == 2 ? 5 : 7))];
        stage8(src + off, Wb + w * 262144 + off);
    } else if (c < 655616) {
        const int c3 = c - 655360;          // 0..255
        const int bsel = c3 >> 6;
        const int off = (c3 & 63) * 8;
        const T* src = (const T*)in[bsel == 0 ? 2 : (bsel == 1 ? 4 : (bsel == 2 ? 6 : 8))];
        stage8(src + off, bb + bsel * 512 + off);
    }
}

__global__ __launch_bounds__(256) void convert_all(
    const void* x, const void* Wq, const void* bq,
    const void* Wk, const void* bk, const void* Wv, const void* bv,
    const void* Wo, const void* bo,
    short* __restrict__ xb, short* __restrict__ Wb, short* __restrict__ bb)
{
    const void* in[9] = {x, Wq, bq, Wk, bk, Wv, bv, Wo, bo};
    const int mode = probe_mode(x);
    const int c = blockIdx.x * 256 + threadIdx.x;
    if (mode) convert_body<float>(in, xb, Wb, bb, c);
    else      convert_body<bf16>(in, xb, Wb, bb, c);
}

// ---------------------------------------------------------------------------
// Kernel 2: fused QKV projection via gload_lds + XOR-SWIZZLED LDS layout.
// The packed stride-64 layout forced by gload_lds wraps banks every row ->
// fragment reads were ~16-way bank-conflicted.  Swizzle: row r's 16B chunk g
// lives at physical slot g^(r&7); staging lane loads global chunk
// (lane&7)^(lane>>3); reads use slot (ks*4+quad)^(lm&7).  Bit-identical math.
// ---------------------------------------------------------------------------
__global__ __launch_bounds__(256) void qkv_gemm_dl(
    const short* __restrict__ xb, const short* __restrict__ Wb,
    const short* __restrict__ bb,
    bf16* __restrict__ Qf, bf16* __restrict__ Kf, bf16* __restrict__ Vf)
{
    const int mtile = blockIdx.x;            // 0..63
    const int ntile = blockIdx.y;            // 0..11
    const int which = ntile >> 2;
    const short* W = Wb + (size_t)which * 262144;
    const bf16* bias = (const bf16*)(bb + which * 512);
    bf16* outp = (which == 0) ? Qf : ((which == 1) ? Kf : Vf);
    const int nbase = (ntile & 3) * 128;
    const int mbase = mtile * 128;

    __shared__ short As[128 * 64];   // packed stride 64, XOR-swizzled slots
    __shared__ short Bs[128 * 64];

    const int tid  = threadIdx.x;
    const int wave = tid >> 6, lane = tid & 63;
    const int wm = wave >> 1, wn = wave & 1;
    const int lm = lane & 15, quad = lane >> 4;
    const int srow = lane >> 3;                    // 0..7 within issue
    const int scol = ((lane & 7) ^ srow) * 8;      // swizzled source chunk

    floatx4 acc[4][4];
    const floatx4 zero = {0.f, 0.f, 0.f, 0.f};
    #pragma unroll
    for (int mt = 0; mt < 4; ++mt)
        #pragma unroll
        for (int nt = 0; nt < 4; ++nt) acc[mt][nt] = zero;

    for (int kt = 0; kt < EMB; kt += 64) {
        #pragma unroll
        for (int j = 0; j < 4; ++j) {
            const int issue = wave * 4 + j;          // 0..15, 8 rows each
            const int row = issue * 8 + srow;        // row&7 == srow
            gload_lds16(xb + (size_t)(mbase + row) * EMB + kt + scol,
                        &As[issue * 512]);
            gload_lds16(W  + (size_t)(nbase + row) * EMB + kt + scol,
                        &Bs[issue * 512]);
        }
        __syncthreads();
        #pragma unroll
        for (int ks = 0; ks < 2; ++ks) {
            const int sw = ((ks * 4 + quad) ^ (lm & 7)) * 8;   // swizzled slot
            short8 af[4], bfr[4];
            #pragma unroll
            for (int mt = 0; mt < 4; ++mt)
                af[mt] = *reinterpret_cast<const short8*>(
                    &As[(wm * 64 + mt * 16 + lm) * 64 + sw]);
            #pragma unroll
            for (int nt = 0; nt < 4; ++nt)
                bfr[nt] = *reinterpret_cast<const short8*>(
                    &Bs[(wn * 64 + nt * 16 + lm) * 64 + sw]);
            #pragma unroll
            for (int mt = 0; mt < 4; ++mt)
                #pragma unroll
                for (int nt = 0; nt < 4; ++nt)
                    acc[mt][nt] = __builtin_amdgcn_mfma_f32_16x16x32_bf16(
                        af[mt], bfr[nt], acc[mt][nt], 0, 0, 0);
        }
        __syncthreads();
    }

    #pragma unroll
    for (int nt = 0; nt < 4; ++nt) {
        const int col = nbase + wn * 64 + nt * 16 + lm;   // 0..511
        const float bv_ = load_elem(bias, col & 511);
        const int h = col >> 6, d = col & 63;
        #pragma unroll
        for (int mt = 0; mt < 4; ++mt)
            #pragma unroll
            for (int r = 0; r < 4; ++r) {
                const int row = mbase + wm * 64 + mt * 16 + quad * 4 + r;
                const int b = row >> 12, t = row & (T_SEQ - 1);
                float v = acc[mt][nt][r] + bv_;
                if (which != 2) v = (v > 0.f) ? (v + 1.f) : __expf(v);  // elu+1
                outp[(((size_t)(b * NH + h)) * T_SEQ + t) * HD + d] = __float2bfloat16(v);
            }
    }
}

// ---------------------------------------------------------------------------
// Kernel 3: per-chunk (K^T V)^T via MFMA + k column sums + V^T tile export
// (validated r9).  Writes KV increments bf16 [dv][dk].  1024 blocks.
// ---------------------------------------------------------------------------
__global__ __launch_bounds__(256) void chunk_kv(
    const bf16* __restrict__ Kf, const bf16* __restrict__ Vf,
    short* __restrict__ KVc, float* __restrict__ ksum,
    short* __restrict__ Vtg)
{
    const int bh = blockIdx.x >> 6;
    const int c  = blockIdx.x & 63;
    __shared__ short Kt[64 * LDSTR];   // Kt[dk][s]
    __shared__ short Vt[64 * LDSTR];   // Vt[dv][s]
    const int tid = threadIdx.x;
    const bf16* kp = Kf + ((size_t)bh * T_SEQ + c * CS) * HD;
    const bf16* vp = Vf + ((size_t)bh * T_SEQ + c * CS) * HD;
    const size_t toff = ((size_t)bh * NCHUNK + c) * 4096;

    #pragma unroll
    for (int j = 0; j < 2; ++j) {
        const int u = j * 256 + tid;
        const int e0 = u * 8;
        const int s = e0 >> 6, d0 = e0 & 63;
        short8 ku = *reinterpret_cast<const short8*>(kp + e0);
        short8 vu = *reinterpret_cast<const short8*>(vp + e0);
        #pragma unroll
        for (int i = 0; i < 8; ++i) {
            Kt[(d0 + i) * LDSTR + s] = ku[i];
            Vt[(d0 + i) * LDSTR + s] = vu[i];
        }
    }
    __syncthreads();

    // export V^T tile: packed [dv][s] stride 64, coalesced 16B stores
    #pragma unroll
    for (int j = 0; j < 2; ++j) {
        const int u = j * 256 + tid;
        const int e0 = u * 8;
        const int row = e0 >> 6, col = e0 & 63;
        *reinterpret_cast<short8*>(Vtg + toff + row * 64 + col) =
            *reinterpret_cast<const short8*>(&Vt[row * LDSTR + col]);
    }

    const int w = tid >> 6, lane = tid & 63;
    const int lm = lane & 15, quad = lane >> 4;

    floatx4 acc[4];
    const floatx4 zero = {0.f, 0.f, 0.f, 0.f};
    #pragma unroll
    for (int nt = 0; nt < 4; ++nt) acc[nt] = zero;

    #pragma unroll
    for (int ks = 0; ks < 2; ++ks) {
        short8 av = *reinterpret_cast<const short8*>(
            &Vt[(w * 16 + lm) * LDSTR + ks * 32 + quad * 8]);   // A: rows = dv
        #pragma unroll
        for (int nt = 0; nt < 4; ++nt) {
            short8 bk = *reinterpret_cast<const short8*>(
                &Kt[(nt * 16 + lm) * LDSTR + ks * 32 + quad * 8]);  // B: cols = dk
            acc[nt] = __builtin_amdgcn_mfma_f32_16x16x32_bf16(av, bk, acc[nt], 0, 0, 0);
        }
    }

    #pragma unroll
    for (int nt = 0; nt < 4; ++nt)
        #pragma unroll
        for (int r = 0; r < 4; ++r) {
            const int dv = w * 16 + quad * 4 + r;
            const int dk = nt * 16 + lm;
            KVc[toff + dv * 64 + dk] = f2bs(acc[nt][r]);
        }

    if (tid < 64) {
        float s = 0.f;
        #pragma unroll 8
        for (int t = 0; t < 64; ++t) s += bs2f(Kt[tid * LDSTR + t]);
        ksum[((size_t)bh * NCHUNK + c) * 64 + tid] = s;
    }
}

// ---------------------------------------------------------------------------
// Kernel 4: exclusive prefix over chunks — element-parallel register scan,
// bf16 in-place, fp32 accumulation (validated r9).  256 blocks.
// ---------------------------------------------------------------------------
__global__ __launch_bounds__(256) void prefix_kv(
    short* __restrict__ KVc, float* __restrict__ ksum)
{
    const int bh   = blockIdx.x >> 4;
    const int part = blockIdx.x & 15;
    const int tid  = threadIdx.x;
    const int e    = part * 256 + tid;
    short* base = KVc + (size_t)bh * NCHUNK * 4096 + e;

    float s = 0.f;
    #pragma unroll
    for (int cb = 0; cb < 4; ++cb) {
        float v[16];
        #pragma unroll
        for (int i = 0; i < 16; ++i) v[i] = bs2f(base[(size_t)(cb * 16 + i) * 4096]);
        #pragma unroll
        for (int i = 0; i < 16; ++i) {
            const float tmp = v[i];
            base[(size_t)(cb * 16 + i) * 4096] = f2bs(s);
            s += tmp;
        }
    }

    if (part == 0 && tid < 64) {
        float* zb = ksum + (size_t)bh * NCHUNK * 64 + tid;
        float z = 0.f;
        #pragma unroll
        for (int cb = 0; cb < 4; ++cb) {
            float v[16];
            #pragma unroll
            for (int i = 0; i < 16; ++i) v[i] = zb[(size_t)(cb * 16 + i) * 64];
            #pragma unroll
            for (int i = 0; i < 16; ++i) {
                const float tmp = v[i];
                zb[(size_t)(cb * 16 + i) * 64] = z;
                z += tmp;
            }
        }
    }
}

// ---------------------------------------------------------------------------
// Kernel 5: per-chunk attention — barrier-free, direct-fragment loads
// (validated r9).  1024 blocks.
// ---------------------------------------------------------------------------
__global__ __launch_bounds__(256) void attn_lite(
    const bf16* __restrict__ Qf, const bf16* __restrict__ Kf,
    const short* __restrict__ Vtg, const short* __restrict__ KVc,
    const float* __restrict__ ksum, bf16* __restrict__ Of)
{
    const int bh = blockIdx.x >> 6;
    const int c  = blockIdx.x & 63;
    const int b  = bh >> 3, h = bh & 7;

    __shared__ short Ps[64 * LDSTR];   // masked scores P[t][s]
    __shared__ float qzbuf[64];        // q.z per row

    const int tid = threadIdx.x;
    const int w = tid >> 6, lane = tid & 63;
    const int lm = lane & 15, quad = lane >> 4;
    const size_t coff = ((size_t)bh * T_SEQ + c * CS) * HD;
    const size_t toff = ((size_t)bh * NCHUNK + c) * 4096;   // tile base

    // ---- A-fragments of Q (row w*16+lm), direct from global ----
    short8 aq[2];
    #pragma unroll
    for (int ks = 0; ks < 2; ++ks)
        aq[ks] = *reinterpret_cast<const short8*>(
            Qf + coff + (w * 16 + lm) * HD + ks * 32 + quad * 8);

    // ---- q.z partials: lane holds Q[w*16+lm][ks*32+quad*8+j] ----
    const float* zp = ksum + ((size_t)bh * NCHUNK + c) * 64;
    float qz = 0.f;
    #pragma unroll
    for (int ks = 0; ks < 2; ++ks) {
        const float4 z0 = *reinterpret_cast<const float4*>(zp + ks * 32 + quad * 8);
        const float4 z1 = *reinterpret_cast<const float4*>(zp + ks * 32 + quad * 8 + 4);
        qz += bs2f(aq[ks][0]) * z0.x + bs2f(aq[ks][1]) * z0.y
            + bs2f(aq[ks][2]) * z0.z + bs2f(aq[ks][3]) * z0.w
            + bs2f(aq[ks][4]) * z1.x + bs2f(aq[ks][5]) * z1.y
            + bs2f(aq[ks][6]) * z1.z + bs2f(aq[ks][7]) * z1.w;
    }
    qz += __shfl_xor(qz, 16);
    qz += __shfl_xor(qz, 32);          // all 4 quads now hold full q.z of row lm
    if (quad == 0) qzbuf[w * 16 + lm] = qz;   // wave-local write

    // ---- P = Q K^T (K B-frags direct from global, row-major k=d) ----
    const floatx4 zero = {0.f, 0.f, 0.f, 0.f};
    floatx4 pacc[4];
    #pragma unroll
    for (int nt = 0; nt < 4; ++nt) pacc[nt] = zero;
    #pragma unroll
    for (int ks = 0; ks < 2; ++ks)
        #pragma unroll
        for (int nt = 0; nt < 4; ++nt) {
            short8 bk = *reinterpret_cast<const short8*>(
                Kf + coff + (nt * 16 + lm) * HD + ks * 32 + quad * 8);
            pacc[nt] = __builtin_amdgcn_mfma_f32_16x16x32_bf16(aq[ks], bk, pacc[nt], 0, 0, 0);
        }

    // mask + write Ps (wave-local rows) + register rowsums
    float tot[4] = {0.f, 0.f, 0.f, 0.f};
    #pragma unroll
    for (int nt = 0; nt < 4; ++nt)
        #pragma unroll
        for (int r = 0; r < 4; ++r) {
            const int t = w * 16 + quad * 4 + r;
            const int s = nt * 16 + lm;
            const float m = (s <= t) ? pacc[nt][r] : 0.f;
            Ps[t * LDSTR + s] = f2bs(m);
            tot[r] += m;
        }
    #pragma unroll
    for (int mask = 1; mask < 16; mask <<= 1)
        #pragma unroll
        for (int r = 0; r < 4; ++r) tot[r] += __shfl_xor(tot[r], mask);

    // ---- O = Q @ S_prev^T (S^T tile bf16, direct B-frags) ----
    floatx4 oacc[4];
    #pragma unroll
    for (int nt = 0; nt < 4; ++nt) oacc[nt] = zero;
    #pragma unroll
    for (int ks = 0; ks < 2; ++ks)
        #pragma unroll
        for (int nt = 0; nt < 4; ++nt) {
            short8 bs = *reinterpret_cast<const short8*>(
                KVc + toff + (nt * 16 + lm) * 64 + ks * 32 + quad * 8);
            oacc[nt] = __builtin_amdgcn_mfma_f32_16x16x32_bf16(aq[ks], bs, oacc[nt], 0, 0, 0);
        }

    // ---- O += P V (P A-frags from own wave's Ps rows; V^T direct) ----
    #pragma unroll
    for (int ks = 0; ks < 2; ++ks) {
        short8 ap = *reinterpret_cast<const short8*>(
            &Ps[(w * 16 + lm) * LDSTR + ks * 32 + quad * 8]);
        #pragma unroll
        for (int nt = 0; nt < 4; ++nt) {
            short8 bv = *reinterpret_cast<const short8*>(
                Vtg + toff + (nt * 16 + lm) * 64 + ks * 32 + quad * 8);
            oacc[nt] = __builtin_amdgcn_mfma_f32_16x16x32_bf16(ap, bv, oacc[nt], 0, 0, 0);
        }
    }

    // ---- denominator + store ----
    float rdenl[4];
    #pragma unroll
    for (int r = 0; r < 4; ++r)
        rdenl[r] = 1.f / (tot[r] + qzbuf[w * 16 + quad * 4 + r] + 1e-6f);

    #pragma unroll
    for (int nt = 0; nt < 4; ++nt)
        #pragma unroll
        for (int r = 0; r < 4; ++r) {
            const int t  = w * 16 + quad * 4 + r;
            const int dv = nt * 16 + lm;
            const int tg = c * CS + t;
            Of[((size_t)(b * T_SEQ + tg)) * EMB + h * HD + dv] =
                __float2bfloat16(oacc[nt][r] * rdenl[r]);
        }
}

// ---------------------------------------------------------------------------
// Kernel 6: output projection via gload_lds + XOR swizzle, self-probing
// store dtype.  out = Of @ Wo^T + bo.  Grid (64, 4).
// ---------------------------------------------------------------------------
__global__ __launch_bounds__(256) void out_proj_dl(
    const void* __restrict__ xprobe,
    const short* __restrict__ A, const short* __restrict__ Wb,
    const short* __restrict__ bb, void* __restrict__ out)
{
    const int mode = probe_mode(xprobe);

    const int mbase = blockIdx.x * 128;
    const int nbase = blockIdx.y * 128;
    const short* W = Wb + (size_t)3 * 262144;
    const bf16* bias = (const bf16*)(bb + 3 * 512);

    __shared__ short As[128 * 64];
    __shared__ short Bs[128 * 64];

    const int tid  = threadIdx.x;
    const int wave = tid >> 6, lane = tid & 63;
    const int wm = wave >> 1, wn = wave & 1;
    const int lm = lane & 15, quad = lane >> 4;
    const int srow = lane >> 3;
    const int scol = ((lane & 7) ^ srow) * 8;      // swizzled source chunk

    floatx4 acc[4][4];
    const floatx4 zero = {0.f, 0.f, 0.f, 0.f};
    #pragma unroll
    for (int mt = 0; mt < 4; ++mt)
        #pragma unroll
        for (int nt = 0; nt < 4; ++nt) acc[mt][nt] = zero;

    for (int kt = 0; kt < EMB; kt += 64) {
        #pragma unroll
        for (int j = 0; j < 4; ++j) {
            const int issue = wave * 4 + j;
            const int row = issue * 8 + srow;
            gload_lds16(A + (size_t)(mbase + row) * EMB + kt + scol,
                        &As[issue * 512]);
            gload_lds16(W + (size_t)(nbase + row) * EMB + kt + scol,
                        &Bs[issue * 512]);
        }
        __syncthreads();
        #pragma unroll
        for (int ks = 0; ks < 2; ++ks) {
            const int sw = ((ks * 4 + quad) ^ (lm & 7)) * 8;   // swizzled slot
            short8 af[4], bfr[4];
            #pragma unroll
            for (int mt = 0; mt < 4; ++mt)
                af[mt] = *reinterpret_cast<const short8*>(
                    &As[(wm * 64 + mt * 16 + lm) * 64 + sw]);
            #pragma unroll
            for (int nt = 0; nt < 4; ++nt)
                bfr[nt] = *reinterpret_cast<const short8*>(
                    &Bs[(wn * 64 + nt * 16 + lm) * 64 + sw]);
            #pragma unroll
            for (int mt = 0; mt < 4; ++mt)
                #pragma unroll
                for (int nt = 0; nt < 4; ++nt)
                    acc[mt][nt] = __builtin_amdgcn_mfma_f32_16x16x32_bf16(
                        af[mt], bfr[nt], acc[mt][nt], 0, 0, 0);
        }
        __syncthreads();
    }

    #pragma unroll
    for (int nt = 0; nt < 4; ++nt) {
        const int col = nbase + wn * 64 + nt * 16 + lm;
        const float bv_ = load_elem(bias, col);
        #pragma unroll
        for (int mt = 0; mt < 4; ++mt)
            #pragma unroll
            for (int r = 0; r < 4; ++r) {
                const int row = mbase + wm * 64 + mt * 16 + quad * 4 + r;
                const float v = acc[mt][nt][r] + bv_;
                if (mode) ((float*)out)[(size_t)row * EMB + col] = v;
                else      ((bf16*)out)[(size_t)row * EMB + col] = __float2bfloat16(v);
            }
    }
}

// ---------------------------------------------------------------------------
extern "C" void kernel_launch(void* const* d_in, const int* in_sizes, int n_in,
                              void* d_out, int out_size, void* d_ws, size_t ws_size,
                              hipStream_t stream)
{
    // workspace (~58.3 MB):
    //   reserved 64 B
    //   Qf/Kf/Vf : bf16 4,194,304 each                    (24 MB)
    //   union  : [ KVc bf16 4,194,304 | xb bf16 4,194,304 ]  (8 MB)
    //   ksum   : fp32 65,536                               (0.25 MB)
    //   Of     : bf16 4,194,304                            (8 MB)
    //   Wb     : bf16 4x262,144                            (2 MB)
    //   bb     : bf16 4x512                                (4 KB)
    //   Vtg    : bf16 4,194,304 (V^T tiles)                (8 MB)
    bf16* Qf = (bf16*)((char*)d_ws + 64);
    bf16* Kf = Qf + 4194304;
    bf16* Vf = Kf + 4194304;
    short* KVc = (short*)(Vf + 4194304);
    short* xb = KVc;                        // aliased (disjoint lifetime)
    float* ks = (float*)(KVc + 4194304);
    bf16* Of = (bf16*)(ks + 65536);
    short* Wb = (short*)(Of + 4194304);
    short* bb = Wb + 1048576;
    short* Vtg = bb + 2048;

    convert_all<<<dim3(2561), 256, 0, stream>>>(
        d_in[0], d_in[1], d_in[2], d_in[3], d_in[4],
        d_in[5], d_in[6], d_in[7], d_in[8], xb, Wb, bb);

    qkv_gemm_dl<<<dim3(64, 12), 256, 0, stream>>>(xb, Wb, bb, Qf, Kf, Vf);
    chunk_kv<<<dim3(BHEADS * NCHUNK), 256, 0, stream>>>(Kf, Vf, KVc, ks, Vtg);
    prefix_kv<<<dim3(BHEADS * 16), 256, 0, stream>>>(KVc, ks);
    attn_lite<<<dim3(BHEADS * NCHUNK), 256, 0, stream>>>(Qf, Kf, Vtg, KVc, ks, Of);

    out_proj_dl<<<dim3(64, 4), 256, 0, stream>>>(
        d_in[0], (const short*)Of, Wb, bb, d_out);
}

// Round 11
// 161.904 us; speedup vs baseline: 1.1591x; 1.0021x over previous
//
#include <hip/hip_runtime.h>
#include <hip/hip_bf16.h>

// Problem constants: B=2, T=4096, E=512, H=8, D=64
#define T_SEQ 4096
#define EMB   512
#define NH    8
#define HD    64
#define BATCH 2
#define M_ROWS (BATCH * T_SEQ)   // 8192
#define NCHUNK 64                // T / CS
#define CS     64                // chunk size
#define BHEADS (BATCH * NH)      // 16

using bf16 = __hip_bfloat16;
typedef __attribute__((ext_vector_type(8))) short short8;   // 8 bf16 = 4 VGPR
typedef __attribute__((ext_vector_type(4))) float floatx4;  // MFMA acc

__device__ __forceinline__ float bs2f(short s) {
    return __uint_as_float(((unsigned)(unsigned short)s) << 16);
}
__device__ __forceinline__ short f2bs(float f) {
    bf16 h = __float2bfloat16(f);
    return *reinterpret_cast<short*>(&h);
}
__device__ __forceinline__ float load_elem(const bf16* p, size_t i) {
    return __bfloat162float(p[i]);
}
// convert 8 consecutive elems (any dtype) -> bf16, 16B write
__device__ __forceinline__ void stage8(const bf16* g, short* l) {
    *reinterpret_cast<short8*>(l) = *reinterpret_cast<const short8*>(g);
}
__device__ __forceinline__ void stage8(const float* g, short* l) {
    float4 a = *reinterpret_cast<const float4*>(g);
    float4 b = *reinterpret_cast<const float4*>(g + 4);
    short8 v;
    v[0] = f2bs(a.x); v[1] = f2bs(a.y); v[2] = f2bs(a.z); v[3] = f2bs(a.w);
    v[4] = f2bs(b.x); v[5] = f2bs(b.y); v[6] = f2bs(b.z); v[7] = f2bs(b.w);
    *reinterpret_cast<short8*>(l) = v;
}

// async global->LDS: each lane copies 16B to (wave-uniform base) + lane*16
__device__ __forceinline__ void gload_lds16(const short* g, short* l) {
    __builtin_amdgcn_global_load_lds(
        (const __attribute__((address_space(1))) void*)g,
        (__attribute__((address_space(3))) void*)l, 16, 0, 0);
}

#define LDSTR 72    // padded LDS row stride (shorts) for transposed tiles
#define CSTR  136   // C-tile row stride (shorts): 272B rows, 16B-aligned, bank-shifted

// ---------------------------------------------------------------------------
// In-block dtype probe (validated r7).  1 = fp32, 0 = bf16.  256 threads.
// ---------------------------------------------------------------------------
__device__ __forceinline__ int probe_mode(const void* x) {
    const uint4* p = (const uint4*)x;
    const int tid = threadIdx.x;
    bool bad = false;
    #pragma unroll
    for (int i = 0; i < 2; ++i) {
        uint4 u = p[tid + i * 256];
        const unsigned w[4] = {u.x, u.y, u.z, u.w};
        #pragma unroll
        for (int k = 0; k < 4; ++k) {
            const float f = __uint_as_float(w[k] << 16);   // low half
            if (!(fabsf(f) <= 1e9f)) bad = true;
        }
    }
    return __syncthreads_or(bad ? 1 : 0) ? 1 : 0;
}

// ---------------------------------------------------------------------------
// Kernel 1: convert x, Wq/Wk/Wv/Wo, biases -> bf16 ws (validated r7).
// ---------------------------------------------------------------------------
template <typename T>
__device__ __forceinline__ void convert_body(
    const void* const* in, short* xb, short* Wb, short* bb, int c)
{
    if (c < 524288) {
        stage8((const T*)in[0] + (size_t)c * 8, xb + (size_t)c * 8);
    } else if (c < 655360) {
        const int c2 = c - 524288;
        const int w = c2 >> 15;             // 0..3 : Wq Wk Wv Wo
        const int off = (c2 & 32767) * 8;
        const T* src = (const T*)in[w == 0 ? 1 : (w == 1 ? 3 : (w == 2 ? 5 : 7))];
        stage8(src + off, Wb + w * 262144 + off);
    } else if (c < 655616) {
        const int c3 = c - 655360;          // 0..255
        const int bsel = c3 >> 6;
        const int off = (c3 & 63) * 8;
        const T* src = (const T*)in[bsel == 0 ? 2 : (bsel == 1 ? 4 : (bsel == 2 ? 6 : 8))];
        stage8(src + off, bb + bsel * 512 + off);
    }
}

__global__ __launch_bounds__(256) void convert_all(
    const void* x, const void* Wq, const void* bq,
    const void* Wk, const void* bk, const void* Wv, const void* bv,
    const void* Wo, const void* bo,
    short* __restrict__ xb, short* __restrict__ Wb, short* __restrict__ bb)
{
    const void* in[9] = {x, Wq, bq, Wk, bk, Wv, bv, Wo, bo};
    const int mode = probe_mode(x);
    const int c = blockIdx.x * 256 + threadIdx.x;
    if (mode) convert_body<float>(in, xb, Wb, bb, c);
    else      convert_body<bf16>(in, xb, Wb, bb, c);
}

// ---------------------------------------------------------------------------
// Kernel 2: fused QKV projection, gload_lds + XOR swizzle (r10) + NEW
// coalesced epilogue: C-tile staged to LDS (bf16), 16B/lane stores replace
// 64 scalar 2B scattered stores per thread.
// ---------------------------------------------------------------------------
__global__ __launch_bounds__(256) void qkv_gemm_dl(
    const short* __restrict__ xb, const short* __restrict__ Wb,
    const short* __restrict__ bb,
    bf16* __restrict__ Qf, bf16* __restrict__ Kf, bf16* __restrict__ Vf)
{
    const int mtile = blockIdx.x;            // 0..63
    const int ntile = blockIdx.y;            // 0..11
    const int which = ntile >> 2;
    const short* W = Wb + (size_t)which * 262144;
    const bf16* bias = (const bf16*)(bb + which * 512);
    bf16* outp = (which == 0) ? Qf : ((which == 1) ? Kf : Vf);
    const int nbase = (ntile & 3) * 128;
    const int mbase = mtile * 128;

    __shared__ short smem[128 * CSTR];   // union: As+Bs (32KB) / C-tile (34KB)
    short* As = smem;                    // 128x64 packed, swizzled
    short* Bs = smem + 8192;

    const int tid  = threadIdx.x;
    const int wave = tid >> 6, lane = tid & 63;
    const int wm = wave >> 1, wn = wave & 1;
    const int lm = lane & 15, quad = lane >> 4;
    const int srow = lane >> 3;                    // 0..7 within issue
    const int scol = ((lane & 7) ^ srow) * 8;      // swizzled source chunk

    floatx4 acc[4][4];
    const floatx4 zero = {0.f, 0.f, 0.f, 0.f};
    #pragma unroll
    for (int mt = 0; mt < 4; ++mt)
        #pragma unroll
        for (int nt = 0; nt < 4; ++nt) acc[mt][nt] = zero;

    for (int kt = 0; kt < EMB; kt += 64) {
        #pragma unroll
        for (int j = 0; j < 4; ++j) {
            const int issue = wave * 4 + j;          // 0..15, 8 rows each
            const int row = issue * 8 + srow;        // row&7 == srow
            gload_lds16(xb + (size_t)(mbase + row) * EMB + kt + scol,
                        &As[issue * 512]);
            gload_lds16(W  + (size_t)(nbase + row) * EMB + kt + scol,
                        &Bs[issue * 512]);
        }
        __syncthreads();
        #pragma unroll
        for (int ks = 0; ks < 2; ++ks) {
            const int sw = ((ks * 4 + quad) ^ (lm & 7)) * 8;   // swizzled slot
            short8 af[4], bfr[4];
            #pragma unroll
            for (int mt = 0; mt < 4; ++mt)
                af[mt] = *reinterpret_cast<const short8*>(
                    &As[(wm * 64 + mt * 16 + lm) * 64 + sw]);
            #pragma unroll
            for (int nt = 0; nt < 4; ++nt)
                bfr[nt] = *reinterpret_cast<const short8*>(
                    &Bs[(wn * 64 + nt * 16 + lm) * 64 + sw]);
            #pragma unroll
            for (int mt = 0; mt < 4; ++mt)
                #pragma unroll
                for (int nt = 0; nt < 4; ++nt)
                    acc[mt][nt] = __builtin_amdgcn_mfma_f32_16x16x32_bf16(
                        af[mt], bfr[nt], acc[mt][nt], 0, 0, 0);
        }
        __syncthreads();
    }

    // ---- coalesced epilogue: stage C-tile (bf16) then vector stores ----
    short* Cs = smem;                    // reuse staging space
    #pragma unroll
    for (int nt = 0; nt < 4; ++nt) {
        const int col = wn * 64 + nt * 16 + lm;       // local 0..127
        const float bv_ = load_elem(bias, nbase + col);
        #pragma unroll
        for (int mt = 0; mt < 4; ++mt)
            #pragma unroll
            for (int r = 0; r < 4; ++r) {
                const int row = wm * 64 + mt * 16 + quad * 4 + r;
                float v = acc[mt][nt][r] + bv_;
                if (which != 2) v = (v > 0.f) ? (v + 1.f) : __expf(v);  // elu+1
                Cs[row * CSTR + col] = f2bs(v);
            }
    }
    __syncthreads();
    #pragma unroll
    for (int j = 0; j < 8; ++j) {
        const int u = j * 256 + tid;       // 0..2047 chunks of 8
        const int row = u >> 4;            // 0..127
        const int cc = (u & 15) * 8;       // 0..120
        const int gcol = nbase + cc;
        const int h = gcol >> 6, d = gcol & 63;
        const int grow = mbase + row;
        const int b = grow >> 12, t = grow & (T_SEQ - 1);
        *reinterpret_cast<short8*>(
            outp + (((size_t)(b * NH + h)) * T_SEQ + t) * HD + d) =
            *reinterpret_cast<const short8*>(&Cs[row * CSTR + cc]);
    }
}

// ---------------------------------------------------------------------------
// Kernel 3: per-chunk (K^T V)^T via MFMA + k column sums + V^T tile export
// (validated r9).  Writes KV increments bf16 [dv][dk].  1024 blocks.
// ---------------------------------------------------------------------------
__global__ __launch_bounds__(256) void chunk_kv(
    const bf16* __restrict__ Kf, const bf16* __restrict__ Vf,
    short* __restrict__ KVc, float* __restrict__ ksum,
    short* __restrict__ Vtg)
{
    const int bh = blockIdx.x >> 6;
    const int c  = blockIdx.x & 63;
    __shared__ short Kt[64 * LDSTR];   // Kt[dk][s]
    __shared__ short Vt[64 * LDSTR];   // Vt[dv][s]
    const int tid = threadIdx.x;
    const bf16* kp = Kf + ((size_t)bh * T_SEQ + c * CS) * HD;
    const bf16* vp = Vf + ((size_t)bh * T_SEQ + c * CS) * HD;
    const size_t toff = ((size_t)bh * NCHUNK + c) * 4096;

    #pragma unroll
    for (int j = 0; j < 2; ++j) {
        const int u = j * 256 + tid;
        const int e0 = u * 8;
        const int s = e0 >> 6, d0 = e0 & 63;
        short8 ku = *reinterpret_cast<const short8*>(kp + e0);
        short8 vu = *reinterpret_cast<const short8*>(vp + e0);
        #pragma unroll
        for (int i = 0; i < 8; ++i) {
            Kt[(d0 + i) * LDSTR + s] = ku[i];
            Vt[(d0 + i) * LDSTR + s] = vu[i];
        }
    }
    __syncthreads();

    // export V^T tile: packed [dv][s] stride 64, coalesced 16B stores
    #pragma unroll
    for (int j = 0; j < 2; ++j) {
        const int u = j * 256 + tid;
        const int e0 = u * 8;
        const int row = e0 >> 6, col = e0 & 63;
        *reinterpret_cast<short8*>(Vtg + toff + row * 64 + col) =
            *reinterpret_cast<const short8*>(&Vt[row * LDSTR + col]);
    }

    const int w = tid >> 6, lane = tid & 63;
    const int lm = lane & 15, quad = lane >> 4;

    floatx4 acc[4];
    const floatx4 zero = {0.f, 0.f, 0.f, 0.f};
    #pragma unroll
    for (int nt = 0; nt < 4; ++nt) acc[nt] = zero;

    #pragma unroll
    for (int ks = 0; ks < 2; ++ks) {
        short8 av = *reinterpret_cast<const short8*>(
            &Vt[(w * 16 + lm) * LDSTR + ks * 32 + quad * 8]);   // A: rows = dv
        #pragma unroll
        for (int nt = 0; nt < 4; ++nt) {
            short8 bk = *reinterpret_cast<const short8*>(
                &Kt[(nt * 16 + lm) * LDSTR + ks * 32 + quad * 8]);  // B: cols = dk
            acc[nt] = __builtin_amdgcn_mfma_f32_16x16x32_bf16(av, bk, acc[nt], 0, 0, 0);
        }
    }

    #pragma unroll
    for (int nt = 0; nt < 4; ++nt)
        #pragma unroll
        for (int r = 0; r < 4; ++r) {
            const int dv = w * 16 + quad * 4 + r;
            const int dk = nt * 16 + lm;
            KVc[toff + dv * 64 + dk] = f2bs(acc[nt][r]);
        }

    if (tid < 64) {
        float s = 0.f;
        #pragma unroll 8
        for (int t = 0; t < 64; ++t) s += bs2f(Kt[tid * LDSTR + t]);
        ksum[((size_t)bh * NCHUNK + c) * 64 + tid] = s;
    }
}

// ---------------------------------------------------------------------------
// Kernel 4: exclusive prefix over chunks — element-parallel register scan,
// bf16 in-place, fp32 accumulation (validated r9).  256 blocks.
// ---------------------------------------------------------------------------
__global__ __launch_bounds__(256) void prefix_kv(
    short* __restrict__ KVc, float* __restrict__ ksum)
{
    const int bh   = blockIdx.x >> 4;
    const int part = blockIdx.x & 15;
    const int tid  = threadIdx.x;
    const int e    = part * 256 + tid;
    short* base = KVc + (size_t)bh * NCHUNK * 4096 + e;

    float s = 0.f;
    #pragma unroll
    for (int cb = 0; cb < 4; ++cb) {
        float v[16];
        #pragma unroll
        for (int i = 0; i < 16; ++i) v[i] = bs2f(base[(size_t)(cb * 16 + i) * 4096]);
        #pragma unroll
        for (int i = 0; i < 16; ++i) {
            const float tmp = v[i];
            base[(size_t)(cb * 16 + i) * 4096] = f2bs(s);
            s += tmp;
        }
    }

    if (part == 0 && tid < 64) {
        float* zb = ksum + (size_t)bh * NCHUNK * 64 + tid;
        float z = 0.f;
        #pragma unroll
        for (int cb = 0; cb < 4; ++cb) {
            float v[16];
            #pragma unroll
            for (int i = 0; i < 16; ++i) v[i] = zb[(size_t)(cb * 16 + i) * 64];
            #pragma unroll
            for (int i = 0; i < 16; ++i) {
                const float tmp = v[i];
                zb[(size_t)(cb * 16 + i) * 64] = z;
                z += tmp;
            }
        }
    }
}

// ---------------------------------------------------------------------------
// Kernel 5: per-chunk attention — direct-fragment loads (r9) + NEW coalesced
// O store: O-tile staged into Ps (wave-local rows), 16B/lane stores.
// ---------------------------------------------------------------------------
__global__ __launch_bounds__(256) void attn_lite(
    const bf16* __restrict__ Qf, const bf16* __restrict__ Kf,
    const short* __restrict__ Vtg, const short* __restrict__ KVc,
    const float* __restrict__ ksum, bf16* __restrict__ Of)
{
    const int bh = blockIdx.x >> 6;
    const int c  = blockIdx.x & 63;
    const int b  = bh >> 3, h = bh & 7;

    __shared__ short Ps[64 * LDSTR];   // masked scores P[t][s]; then O-tile
    __shared__ float qzbuf[64];        // q.z per row

    const int tid = threadIdx.x;
    const int w = tid >> 6, lane = tid & 63;
    const int lm = lane & 15, quad = lane >> 4;
    const size_t coff = ((size_t)bh * T_SEQ + c * CS) * HD;
    const size_t toff = ((size_t)bh * NCHUNK + c) * 4096;   // tile base

    // ---- A-fragments of Q (row w*16+lm), direct from global ----
    short8 aq[2];
    #pragma unroll
    for (int ks = 0; ks < 2; ++ks)
        aq[ks] = *reinterpret_cast<const short8*>(
            Qf + coff + (w * 16 + lm) * HD + ks * 32 + quad * 8);

    // ---- q.z partials: lane holds Q[w*16+lm][ks*32+quad*8+j] ----
    const float* zp = ksum + ((size_t)bh * NCHUNK + c) * 64;
    float qz = 0.f;
    #pragma unroll
    for (int ks = 0; ks < 2; ++ks) {
        const float4 z0 = *reinterpret_cast<const float4*>(zp + ks * 32 + quad * 8);
        const float4 z1 = *reinterpret_cast<const float4*>(zp + ks * 32 + quad * 8 + 4);
        qz += bs2f(aq[ks][0]) * z0.x + bs2f(aq[ks][1]) * z0.y
            + bs2f(aq[ks][2]) * z0.z + bs2f(aq[ks][3]) * z0.w
            + bs2f(aq[ks][4]) * z1.x + bs2f(aq[ks][5]) * z1.y
            + bs2f(aq[ks][6]) * z1.z + bs2f(aq[ks][7]) * z1.w;
    }
    qz += __shfl_xor(qz, 16);
    qz += __shfl_xor(qz, 32);          // all 4 quads now hold full q.z of row lm
    if (quad == 0) qzbuf[w * 16 + lm] = qz;   // wave-local write

    // ---- P = Q K^T (K B-frags direct from global, row-major k=d) ----
    const floatx4 zero = {0.f, 0.f, 0.f, 0.f};
    floatx4 pacc[4];
    #pragma unroll
    for (int nt = 0; nt < 4; ++nt) pacc[nt] = zero;
    #pragma unroll
    for (int ks = 0; ks < 2; ++ks)
        #pragma unroll
        for (int nt = 0; nt < 4; ++nt) {
            short8 bk = *reinterpret_cast<const short8*>(
                Kf + coff + (nt * 16 + lm) * HD + ks * 32 + quad * 8);
            pacc[nt] = __builtin_amdgcn_mfma_f32_16x16x32_bf16(aq[ks], bk, pacc[nt], 0, 0, 0);
        }

    // mask + write Ps (wave-local rows) + register rowsums
    float tot[4] = {0.f, 0.f, 0.f, 0.f};
    #pragma unroll
    for (int nt = 0; nt < 4; ++nt)
        #pragma unroll
        for (int r = 0; r < 4; ++r) {
            const int t = w * 16 + quad * 4 + r;
            const int s = nt * 16 + lm;
            const float m = (s <= t) ? pacc[nt][r] : 0.f;
            Ps[t * LDSTR + s] = f2bs(m);
            tot[r] += m;
        }
    #pragma unroll
    for (int mask = 1; mask < 16; mask <<= 1)
        #pragma unroll
        for (int r = 0; r < 4; ++r) tot[r] += __shfl_xor(tot[r], mask);

    // ---- O = Q @ S_prev^T (S^T tile bf16, direct B-frags) ----
    floatx4 oacc[4];
    #pragma unroll
    for (int nt = 0; nt < 4; ++nt) oacc[nt] = zero;
    #pragma unroll
    for (int ks = 0; ks < 2; ++ks)
        #pragma unroll
        for (int nt = 0; nt < 4; ++nt) {
            short8 bs = *reinterpret_cast<const short8*>(
                KVc + toff + (nt * 16 + lm) * 64 + ks * 32 + quad * 8);
            oacc[nt] = __builtin_amdgcn_mfma_f32_16x16x32_bf16(aq[ks], bs, oacc[nt], 0, 0, 0);
        }

    // ---- O += P V (hoist both P A-frags, then MFMA; V^T direct) ----
    short8 ap0 = *reinterpret_cast<const short8*>(
        &Ps[(w * 16 + lm) * LDSTR + 0 * 32 + quad * 8]);
    short8 ap1 = *reinterpret_cast<const short8*>(
        &Ps[(w * 16 + lm) * LDSTR + 1 * 32 + quad * 8]);
    #pragma unroll
    for (int nt = 0; nt < 4; ++nt) {
        short8 bv0 = *reinterpret_cast<const short8*>(
            Vtg + toff + (nt * 16 + lm) * 64 + 0 * 32 + quad * 8);
        short8 bv1 = *reinterpret_cast<const short8*>(
            Vtg + toff + (nt * 16 + lm) * 64 + 1 * 32 + quad * 8);
        oacc[nt] = __builtin_amdgcn_mfma_f32_16x16x32_bf16(ap0, bv0, oacc[nt], 0, 0, 0);
        oacc[nt] = __builtin_amdgcn_mfma_f32_16x16x32_bf16(ap1, bv1, oacc[nt], 0, 0, 0);
    }

    // ---- denominator ----
    float rdenl[4];
    #pragma unroll
    for (int r = 0; r < 4; ++r)
        rdenl[r] = 1.f / (tot[r] + qzbuf[w * 16 + quad * 4 + r] + 1e-6f);

    // ---- stage scaled O into Ps rows (wave-local; write-after-own-read) ----
    #pragma unroll
    for (int nt = 0; nt < 4; ++nt)
        #pragma unroll
        for (int r = 0; r < 4; ++r) {
            const int t = w * 16 + quad * 4 + r;
            Ps[t * LDSTR + nt * 16 + lm] = f2bs(oacc[nt][r] * rdenl[r]);
        }
    __syncthreads();
    // coalesced store: 64x64 tile -> Of (B,T,E); 512 chunks of 8 shorts
    #pragma unroll
    for (int j = 0; j < 2; ++j) {
        const int u = j * 256 + tid;     // 0..511
        const int row = u >> 3;          // t-local 0..63
        const int cc = (u & 7) * 8;      // dv 0..56
        const int tg = c * CS + row;
        *reinterpret_cast<short8*>(
            Of + ((size_t)(b * T_SEQ + tg)) * EMB + h * HD + cc) =
            *reinterpret_cast<const short8*>(&Ps[row * LDSTR + cc]);
    }
}

// ---------------------------------------------------------------------------
// Kernel 6: output projection, gload_lds + XOR swizzle + coalesced epilogue.
// bf16 mode: single bf16 C-tile pass; fp32 mode: two exact fp32 half-tiles.
// ---------------------------------------------------------------------------
__global__ __launch_bounds__(256) void out_proj_dl(
    const void* __restrict__ xprobe,
    const short* __restrict__ A, const short* __restrict__ Wb,
    const short* __restrict__ bb, void* __restrict__ out)
{
    const int mode = probe_mode(xprobe);

    const int mbase = blockIdx.x * 128;
    const int nbase = blockIdx.y * 128;
    const short* W = Wb + (size_t)3 * 262144;
    const bf16* bias = (const bf16*)(bb + 3 * 512);

    __shared__ short smem[128 * CSTR];   // union: As+Bs / C-tile
    short* As = smem;
    short* Bs = smem + 8192;

    const int tid  = threadIdx.x;
    const int wave = tid >> 6, lane = tid & 63;
    const int wm = wave >> 1, wn = wave & 1;
    const int lm = lane & 15, quad = lane >> 4;
    const int srow = lane >> 3;
    const int scol = ((lane & 7) ^ srow) * 8;      // swizzled source chunk

    floatx4 acc[4][4];
    const floatx4 zero = {0.f, 0.f, 0.f, 0.f};
    #pragma unroll
    for (int mt = 0; mt < 4; ++mt)
        #pragma unroll
        for (int nt = 0; nt < 4; ++nt) acc[mt][nt] = zero;

    for (int kt = 0; kt < EMB; kt += 64) {
        #pragma unroll
        for (int j = 0; j < 4; ++j) {
            const int issue = wave * 4 + j;
            const int row = issue * 8 + srow;
            gload_lds16(A + (size_t)(mbase + row) * EMB + kt + scol,
                        &As[issue * 512]);
            gload_lds16(W + (size_t)(nbase + row) * EMB + kt + scol,
                        &Bs[issue * 512]);
        }
        __syncthreads();
        #pragma unroll
        for (int ks = 0; ks < 2; ++ks) {
            const int sw = ((ks * 4 + quad) ^ (lm & 7)) * 8;   // swizzled slot
            short8 af[4], bfr[4];
            #pragma unroll
            for (int mt = 0; mt < 4; ++mt)
                af[mt] = *reinterpret_cast<const short8*>(
                    &As[(wm * 64 + mt * 16 + lm) * 64 + sw]);
            #pragma unroll
            for (int nt = 0; nt < 4; ++nt)
                bfr[nt] = *reinterpret_cast<const short8*>(
                    &Bs[(wn * 64 + nt * 16 + lm) * 64 + sw]);
            #pragma unroll
            for (int mt = 0; mt < 4; ++mt)
                #pragma unroll
                for (int nt = 0; nt < 4; ++nt)
                    acc[mt][nt] = __builtin_amdgcn_mfma_f32_16x16x32_bf16(
                        af[mt], bfr[nt], acc[mt][nt], 0, 0, 0);
        }
        __syncthreads();
    }

    if (mode) {
        // fp32 out: two exact fp32 half-tiles (128x64 floats, 34KB w/ pad)
        float* CsF = (float*)smem;       // stride 68 floats (272B, aligned)
        #pragma unroll
        for (int half = 0; half < 2; ++half) {
            if (half) __syncthreads();   // protect previous half's reads
            if (wn == half) {
                #pragma unroll
                for (int nt = 0; nt < 4; ++nt) {
                    const int col = nt * 16 + lm;          // 0..63 local
                    const float bv_ = load_elem(bias, nbase + half * 64 + col);
                    #pragma unroll
                    for (int mt = 0; mt < 4; ++mt)
                        #pragma unroll
                        for (int r = 0; r < 4; ++r) {
                            const int row = wm * 64 + mt * 16 + quad * 4 + r;
                            CsF[row * 68 + col] = acc[mt][nt][r] + bv_;
                        }
                }
            }
            __syncthreads();
            #pragma unroll
            for (int j = 0; j < 8; ++j) {
                const int u = j * 256 + tid;     // 0..2047 float4 chunks
                const int row = u >> 4;
                const int cc = (u & 15) * 4;
                *reinterpret_cast<float4*>(
                    (float*)out + (size_t)(mbase + row) * EMB + nbase + half * 64 + cc) =
                    *reinterpret_cast<const float4*>(&CsF[row * 68 + cc]);
            }
        }
    } else {
        short* Cs = smem;                // full 128x128 bf16 tile
        #pragma unroll
        for (int nt = 0; nt < 4; ++nt) {
            const int col = wn * 64 + nt * 16 + lm;
            const float bv_ = load_elem(bias, nbase + col);
            #pragma unroll
            for (int mt = 0; mt < 4; ++mt)
                #pragma unroll
                for (int r = 0; r < 4; ++r) {
                    const int row = wm * 64 + mt * 16 + quad * 4 + r;
                    Cs[row * CSTR + col] = f2bs(acc[mt][nt][r] + bv_);
                }
        }
        __syncthreads();
        #pragma unroll
        for (int j = 0; j < 8; ++j) {
            const int u = j * 256 + tid;
            const int row = u >> 4;
            const int cc = (u & 15) * 8;
            *reinterpret_cast<short8*>(
                (bf16*)out + (size_t)(mbase + row) * EMB + nbase + cc) =
                *reinterpret_cast<const short8*>(&Cs[row * CSTR + cc]);
        }
    }
}

// ---------------------------------------------------------------------------
extern "C" void kernel_launch(void* const* d_in, const int* in_sizes, int n_in,
                              void* d_out, int out_size, void* d_ws, size_t ws_size,
                              hipStream_t stream)
{
    // workspace (~58.3 MB):
    //   reserved 64 B
    //   Qf/Kf/Vf : bf16 4,194,304 each                    (24 MB)
    //   union  : [ KVc bf16 4,194,304 | xb bf16 4,194,304 ]  (8 MB)
    //   ksum   : fp32 65,536                               (0.25 MB)
    //   Of     : bf16 4,194,304                            (8 MB)
    //   Wb     : bf16 4x262,144                            (2 MB)
    //   bb     : bf16 4x512                                (4 KB)
    //   Vtg    : bf16 4,194,304 (V^T tiles)                (8 MB)
    bf16* Qf = (bf16*)((char*)d_ws + 64);
    bf16* Kf = Qf + 4194304;
    bf16* Vf = Kf + 4194304;
    short* KVc = (short*)(Vf + 4194304);
    short* xb = KVc;                        // aliased (disjoint lifetime)
    float* ks = (float*)(KVc + 4194304);
    bf16* Of = (bf16*)(ks + 65536);
    short* Wb = (short*)(Of + 4194304);
    short* bb = Wb + 1048576;
    short* Vtg = bb + 2048;

    convert_all<<<dim3(2561), 256, 0, stream>>>(
        d_in[0], d_in[1], d_in[2], d_in[3], d_in[4],
        d_in[5], d_in[6], d_in[7], d_in[8], xb, Wb, bb);

    qkv_gemm_dl<<<dim3(64, 12), 256, 0, stream>>>(xb, Wb, bb, Qf, Kf, Vf);
    chunk_kv<<<dim3(BHEADS * NCHUNK), 256, 0, stream>>>(Kf, Vf, KVc, ks, Vtg);
    prefix_kv<<<dim3(BHEADS * 16), 256, 0, stream>>>(KVc, ks);
    attn_lite<<<dim3(BHEADS * NCHUNK), 256, 0, stream>>>(Qf, Kf, Vtg, KVc, ks, Of);

    out_proj_dl<<<dim3(64, 4), 256, 0, stream>>>(
        d_in[0], (const short*)Of, Wb, bb, d_out);
}